// Round 1
// baseline (2850.438 us; speedup 1.0000x reference)
//
#include <hip/hip_runtime.h>
#include <hip/hip_bf16.h>

// ---------------------------------------------------------------------------
// HyperbolicGNN: BN -> 6x EdgeConv (factored MLP) -> centroid dist -> pool -> FC
// Sizes fixed by the problem.
// ---------------------------------------------------------------------------
#define N_NODES 30000
#define N_EDGES 480000
#define N_GRAPHS 128
#define IN_FEAT 5
#define NUM_CENTROID 100
#define BN_EPS 1e-5f

// ---------------------------------------------------------------------------
// BN statistics: sum and sumsq per feature into acc[0..4], acc[5..9]
// ---------------------------------------------------------------------------
__global__ __launch_bounds__(256) void bn_stats_kernel(
    const float* __restrict__ f, float* __restrict__ acc, int N)
{
    __shared__ float s[10];
    if (threadIdx.x < 10) s[threadIdx.x] = 0.f;
    __syncthreads();
    int n = blockIdx.x * 256 + threadIdx.x;
    if (n < N) {
        #pragma unroll
        for (int k = 0; k < IN_FEAT; ++k) {
            float v = f[n * IN_FEAT + k];
            atomicAdd(&s[k], v);
            atomicAdd(&s[5 + k], v * v);
        }
    }
    __syncthreads();
    if (threadIdx.x < 10) atomicAdd(&acc[threadIdx.x], s[threadIdx.x]);
}

// ---------------------------------------------------------------------------
// Apply BN (training-mode batch stats) -> X0 [N,5]
// ---------------------------------------------------------------------------
__global__ __launch_bounds__(256) void bn_norm_kernel(
    const float* __restrict__ f, const float* __restrict__ acc,
    const float* __restrict__ gamma, const float* __restrict__ beta,
    float* __restrict__ X0, int N)
{
    int i = blockIdx.x * 256 + threadIdx.x;
    if (i >= N * IN_FEAT) return;
    int k = i % IN_FEAT;
    float mu = acc[k] / (float)N;
    float var = acc[5 + k] / (float)N - mu * mu;
    float sc = gamma[k] / sqrtf(var + BN_EPS);
    X0[i] = (f[i] - mu) * sc + beta[k];
}

// ---------------------------------------------------------------------------
// CSR build: histogram of dst, 1-block scan, fill
// ---------------------------------------------------------------------------
__global__ __launch_bounds__(256) void hist_kernel(
    const int* __restrict__ dst, int* __restrict__ counts, int E)
{
    int e = blockIdx.x * 256 + threadIdx.x;
    if (e < E) atomicAdd(&counts[dst[e]], 1);
}

__global__ __launch_bounds__(1024) void scan_kernel(
    const int* __restrict__ counts, int* __restrict__ row_off,
    float* __restrict__ deg_inv, int N)
{
    __shared__ int s[1024];
    const int CH = 30;  // 1024*30 >= 30000
    int t = threadIdx.x;
    int base = t * CH;
    int loc = 0;
    for (int j = 0; j < CH; ++j) {
        int i = base + j;
        if (i < N) loc += counts[i];
    }
    s[t] = loc;
    __syncthreads();
    for (int off = 1; off < 1024; off <<= 1) {
        int v = (t >= off) ? s[t - off] : 0;
        __syncthreads();
        s[t] += v;
        __syncthreads();
    }
    int run = s[t] - loc;  // exclusive prefix
    for (int j = 0; j < CH; ++j) {
        int i = base + j;
        if (i < N) {
            int cv = counts[i];
            row_off[i] = run;
            run += cv;
            deg_inv[i] = 1.0f / fmaxf((float)cv, 1.0f);
        }
    }
    if (t == 1023) row_off[N] = s[1023];
}

__global__ __launch_bounds__(256) void csr_fill_kernel(
    const int* __restrict__ dst, const int* __restrict__ src,
    const int* __restrict__ row_off, int* __restrict__ cursor,
    int* __restrict__ csr_src, int E)
{
    int e = blockIdx.x * 256 + threadIdx.x;
    if (e < E) {
        int d = dst[e];
        int p = atomicAdd(&cursor[d], 1);
        csr_src[row_off[d] + p] = src[e];
    }
}

// ---------------------------------------------------------------------------
// Node transform: U = X @ (W1a - W1b) + b1 ; V = X @ W1b
// W1 is [2F, C] row-major: rows 0..F-1 = W1a, rows F..2F-1 = W1b.
// ---------------------------------------------------------------------------
template <int F, int C>
__global__ __launch_bounds__(256) void node_transform_kernel(
    const float* __restrict__ X, const float* __restrict__ W1,
    const float* __restrict__ b1, float* __restrict__ U,
    float* __restrict__ V, int N)
{
    constexpr int NS = 256 / C;  // nodes per block
    __shared__ float xs[NS][F];
    const int n0 = blockIdx.x * NS;
    for (int i = threadIdx.x; i < NS * F; i += 256) {
        int nn = n0 + i / F;
        xs[i / F][i % F] = (nn < N) ? X[nn * F + i % F] : 0.f;
    }
    __syncthreads();
    const int m = threadIdx.x % C;
    const int ns = threadIdx.x / C;
    const int n = n0 + ns;
    if (n >= N) return;
    float au = b1[m], av = 0.f;
    #pragma unroll 4
    for (int k = 0; k < F; ++k) {
        const float xv = xs[ns][k];
        const float wa = W1[k * C + m];
        const float wb = W1[(F + k) * C + m];
        au += xv * (wa - wb);
        av += xv * wb;
    }
    U[n * C + m] = au;
    V[n * C + m] = av;
}

// ---------------------------------------------------------------------------
// Edge aggregation: for each dst node n:
//   Xout[n] = deg_inv[n] * sum_{e in CSR(n)} relu( relu(U[n]+V[src_e]) @ W2 + b2 )
// One wave per node. W2 staged in LDS. h1 broadcast via LDS (wave-local).
// C in {32, 64, 128} (square layers).
// ---------------------------------------------------------------------------
template <int C>
__global__ __launch_bounds__(256) void edge_agg_kernel(
    const float* __restrict__ U, const float* __restrict__ V,
    const int* __restrict__ row_off, const int* __restrict__ csr_src,
    const float* __restrict__ W2, const float* __restrict__ b2,
    const float* __restrict__ deg_inv, float* __restrict__ Xout, int N)
{
    constexpr int ES  = (C == 32) ? 2 : 1;   // edges per iteration
    constexpr int ML  = (C == 32) ? 32 : 64; // m-lanes per edge
    constexpr int OPL = (C == 128) ? 2 : 1;  // outputs per lane

    __shared__ float w2s[C * C];
    __shared__ float h1s[4][ES][C];

    for (int i = threadIdx.x; i < C * C / 4; i += 256)
        reinterpret_cast<float4*>(w2s)[i] = reinterpret_cast<const float4*>(W2)[i];
    __syncthreads();

    const int wid  = threadIdx.x >> 6;
    const int lane = threadIdx.x & 63;
    const int m    = lane % ML;
    const int es   = lane / ML;
    const int node = blockIdx.x * 4 + wid;
    if (node >= N) return;

    const int rs = row_off[node];
    const int re = row_off[node + 1];

    float u0, u1 = 0.f;
    if constexpr (OPL == 2) {
        u0 = U[node * C + lane];
        u1 = U[node * C + lane + 64];
    } else {
        u0 = U[node * C + m];
    }

    float b2r[OPL];
    #pragma unroll
    for (int o = 0; o < OPL; ++o) b2r[o] = b2[m + o * 64];

    float acc[OPL];
    #pragma unroll
    for (int o = 0; o < OPL; ++o) acc[o] = 0.f;

    for (int base = rs; base < re; base += ES) {
        const int e = base + es;
        const bool valid = (e < re);
        float h0 = 0.f, h1v = 0.f;
        if (valid) {
            const int s = csr_src[e];
            if constexpr (OPL == 2) {
                h0  = fmaxf(u0 + V[s * C + lane], 0.f);
                h1v = fmaxf(u1 + V[s * C + lane + 64], 0.f);
            } else {
                h0 = fmaxf(u0 + V[s * C + m], 0.f);
            }
        }
        if constexpr (OPL == 2) {
            h1s[wid][0][lane]      = h0;
            h1s[wid][0][lane + 64] = h1v;
        } else {
            h1s[wid][es][m] = h0;
        }
        __builtin_amdgcn_wave_barrier();

        float z[OPL];
        #pragma unroll
        for (int o = 0; o < OPL; ++o) z[o] = b2r[o];
        #pragma unroll 4
        for (int k = 0; k < C; ++k) {
            const float hv = h1s[wid][es][k];
            #pragma unroll
            for (int o = 0; o < OPL; ++o)
                z[o] += hv * w2s[k * C + m + o * 64];
        }
        __builtin_amdgcn_wave_barrier();

        if (valid) {
            #pragma unroll
            for (int o = 0; o < OPL; ++o) acc[o] += fmaxf(z[o], 0.f);
        }
    }

    if constexpr (ES == 2) {
        acc[0] += __shfl_xor(acc[0], 32);
    }
    if (lane < ML) {
        const float di = deg_inv[node];
        #pragma unroll
        for (int o = 0; o < OPL; ++o)
            Xout[node * C + m + o * 64] = acc[o] * di;
    }
}

// ---------------------------------------------------------------------------
// Centroid distances: dist[n][c] = sqrt(sum_d (x[n][d]-cent[c][d])^2 + 1e-12)
// Centroids staged transposed in LDS (conflict-free reads).
// ---------------------------------------------------------------------------
__global__ __launch_bounds__(256) void dist_kernel(
    const float* __restrict__ X, const float* __restrict__ centroids,
    float* __restrict__ dist, int N)
{
    __shared__ float centT[128 * NUM_CENTROID];  // [d][c]
    __shared__ float xs[4][128];
    for (int i = threadIdx.x; i < NUM_CENTROID * 128; i += 256) {
        int c = i / 128, d = i % 128;
        centT[d * NUM_CENTROID + c] = centroids[i];
    }
    __syncthreads();
    const int wid = threadIdx.x >> 6;
    const int lane = threadIdx.x & 63;
    const int n = blockIdx.x * 4 + wid;
    if (n >= N) return;
    xs[wid][lane] = X[n * 128 + lane];
    xs[wid][lane + 64] = X[n * 128 + lane + 64];
    __builtin_amdgcn_wave_barrier();
    float a0 = 0.f, a1 = 0.f;
    #pragma unroll 4
    for (int d = 0; d < 128; ++d) {
        const float xv = xs[wid][d];
        const float d0 = xv - centT[d * NUM_CENTROID + lane];
        a0 += d0 * d0;
        if (lane < NUM_CENTROID - 64) {
            const float d1 = xv - centT[d * NUM_CENTROID + lane + 64];
            a1 += d1 * d1;
        }
    }
    dist[n * NUM_CENTROID + lane] = sqrtf(a0 + 1e-12f);
    if (lane < NUM_CENTROID - 64)
        dist[n * NUM_CENTROID + lane + 64] = sqrtf(a1 + 1e-12f);
}

// ---------------------------------------------------------------------------
// Per-graph pooling (graph_id sorted -> binary search range) fused with FC.
// One block per graph.
// ---------------------------------------------------------------------------
__global__ __launch_bounds__(128) void pool_fc_kernel(
    const float* __restrict__ dist, const int* __restrict__ gid,
    const float* __restrict__ fc_w, const float* __restrict__ fc_b,
    float* __restrict__ out, int N)
{
    __shared__ float pooled[NUM_CENTROID];
    const int g = blockIdx.x;
    const int t = threadIdx.x;

    int lo = 0, hi = N;
    while (lo < hi) { int mid = (lo + hi) >> 1; if (gid[mid] < g) lo = mid + 1; else hi = mid; }
    const int start = lo;
    hi = N;
    while (lo < hi) { int mid = (lo + hi) >> 1; if (gid[mid] < g + 1) lo = mid + 1; else hi = mid; }
    const int end = lo;

    if (t < NUM_CENTROID) {
        float s = 0.f;
        for (int n = start; n < end; ++n) s += dist[n * NUM_CENTROID + t];
        pooled[t] = s / fmaxf((float)(end - start), 1.0f);
    }
    __syncthreads();
    if (t < 2) {
        float o = fc_b[t];
        for (int c = 0; c < NUM_CENTROID; ++c) o += pooled[c] * fc_w[c * 2 + t];
        out[g * 2 + t] = o;
    }
}

// ---------------------------------------------------------------------------
// Host launch
// ---------------------------------------------------------------------------
extern "C" void kernel_launch(void* const* d_in, const int* in_sizes, int n_in,
                              void* d_out, int out_size, void* d_ws, size_t ws_size,
                              hipStream_t stream) {
    const float* features = (const float*)d_in[0];
    const int*   src      = (const int*)d_in[1];
    const int*   dst      = (const int*)d_in[2];
    const int*   gid      = (const int*)d_in[3];
    const float* gamma    = (const float*)d_in[4];
    const float* beta     = (const float*)d_in[5];
    const float *W1[6], *b1[6], *W2[6], *b2[6];
    for (int i = 0; i < 6; ++i) {
        W1[i] = (const float*)d_in[6 + 4 * i];
        b1[i] = (const float*)d_in[7 + 4 * i];
        W2[i] = (const float*)d_in[8 + 4 * i];
        b2[i] = (const float*)d_in[9 + 4 * i];
    }
    const float* centroids = (const float*)d_in[30];
    const float* fc_w      = (const float*)d_in[31];
    const float* fc_b      = (const float*)d_in[32];

    const int N = N_NODES, E = N_EDGES;

    // Workspace layout (~76 MB)
    char* p = (char*)d_ws;
    size_t off = 0;
    auto alloc = [&](size_t bytes) {
        void* r = p + off;
        off += (bytes + 255) & ~(size_t)255;
        return r;
    };
    float* X0      = (float*)alloc((size_t)N * 128 * 4);
    float* X1      = (float*)alloc((size_t)N * 128 * 4);
    float* Ubuf    = (float*)alloc((size_t)N * 128 * 4);
    float* Vbuf    = (float*)alloc((size_t)N * 128 * 4);
    float* distb   = (float*)alloc((size_t)N * NUM_CENTROID * 4);
    int*   row_off = (int*)alloc((size_t)(N + 1) * 4);
    int*   csr     = (int*)alloc((size_t)E * 4);
    float* deg_inv = (float*)alloc((size_t)N * 4);
    // zero region: counts + cursor + bnacc (contiguous, one memset)
    char*  zero0   = (char*)(p + off);
    int*   counts  = (int*)alloc((size_t)N * 4);
    int*   cursor  = (int*)alloc((size_t)N * 4);
    float* bnacc   = (float*)alloc(64);
    size_t zbytes  = (size_t)((char*)(p + off) - zero0);

    hipMemsetAsync(zero0, 0, zbytes, stream);

    bn_stats_kernel<<<(N + 255) / 256, 256, 0, stream>>>(features, bnacc, N);
    hist_kernel<<<(E + 255) / 256, 256, 0, stream>>>(dst, counts, E);
    scan_kernel<<<1, 1024, 0, stream>>>(counts, row_off, deg_inv, N);
    csr_fill_kernel<<<(E + 255) / 256, 256, 0, stream>>>(dst, src, row_off, cursor, csr, E);
    bn_norm_kernel<<<(N * IN_FEAT + 255) / 256, 256, 0, stream>>>(features, bnacc, gamma, beta, X0, N);

    // Layer 0: 5 -> 32
    node_transform_kernel<5, 32><<<(N + 7) / 8, 256, 0, stream>>>(X0, W1[0], b1[0], Ubuf, Vbuf, N);
    edge_agg_kernel<32><<<(N + 3) / 4, 256, 0, stream>>>(Ubuf, Vbuf, row_off, csr, W2[0], b2[0], deg_inv, X1, N);
    // Layer 1: 32 -> 32
    node_transform_kernel<32, 32><<<(N + 7) / 8, 256, 0, stream>>>(X1, W1[1], b1[1], Ubuf, Vbuf, N);
    edge_agg_kernel<32><<<(N + 3) / 4, 256, 0, stream>>>(Ubuf, Vbuf, row_off, csr, W2[1], b2[1], deg_inv, X0, N);
    // Layer 2: 32 -> 64
    node_transform_kernel<32, 64><<<(N + 3) / 4, 256, 0, stream>>>(X0, W1[2], b1[2], Ubuf, Vbuf, N);
    edge_agg_kernel<64><<<(N + 3) / 4, 256, 0, stream>>>(Ubuf, Vbuf, row_off, csr, W2[2], b2[2], deg_inv, X1, N);
    // Layer 3: 64 -> 64
    node_transform_kernel<64, 64><<<(N + 3) / 4, 256, 0, stream>>>(X1, W1[3], b1[3], Ubuf, Vbuf, N);
    edge_agg_kernel<64><<<(N + 3) / 4, 256, 0, stream>>>(Ubuf, Vbuf, row_off, csr, W2[3], b2[3], deg_inv, X0, N);
    // Layer 4: 64 -> 128
    node_transform_kernel<64, 128><<<(N + 1) / 2, 256, 0, stream>>>(X0, W1[4], b1[4], Ubuf, Vbuf, N);
    edge_agg_kernel<128><<<(N + 3) / 4, 256, 0, stream>>>(Ubuf, Vbuf, row_off, csr, W2[4], b2[4], deg_inv, X1, N);
    // Layer 5: 128 -> 128
    node_transform_kernel<128, 128><<<(N + 1) / 2, 256, 0, stream>>>(X1, W1[5], b1[5], Ubuf, Vbuf, N);
    edge_agg_kernel<128><<<(N + 3) / 4, 256, 0, stream>>>(Ubuf, Vbuf, row_off, csr, W2[5], b2[5], deg_inv, X0, N);

    dist_kernel<<<(N + 3) / 4, 256, 0, stream>>>(X0, centroids, distb, N);
    pool_fc_kernel<<<N_GRAPHS, 128, 0, stream>>>(distb, gid, fc_w, fc_b, (float*)d_out, N);
}

// Round 2
// 1047.074 us; speedup vs baseline: 2.7223x; 2.7223x over previous
//
#include <hip/hip_runtime.h>
#include <hip/hip_bf16.h>

// ---------------------------------------------------------------------------
// HyperbolicGNN: BN -> 6x EdgeConv -> centroid dist -> pool -> FC
// EdgeConv factored: h1 = relu(U[dst]+V[src]); Xout = deginv * seg_sum(relu(h1@W2+b2))
// Second MLP layer done as edge-parallel bf16 MFMA GEMM + CSR segment-sum.
// ---------------------------------------------------------------------------
#define N_NODES 30000
#define N_EDGES 480000
#define N_GRAPHS 128
#define IN_FEAT 5
#define NUM_CENTROID 100
#define BN_EPS 1e-5f

typedef unsigned int u32;
typedef unsigned short u16;

using short8 = __attribute__((ext_vector_type(8))) short;
using f32x4  = __attribute__((ext_vector_type(4))) float;

__device__ __forceinline__ u16 f2bf(float x) {
    u32 u = __builtin_bit_cast(u32, x);
    u32 r = (u + 0x7FFFu + ((u >> 16) & 1u)) >> 16;
    return (u16)r;
}
__device__ __forceinline__ float bf2f(u16 h) {
    u32 u = ((u32)h) << 16;
    return __builtin_bit_cast(float, u);
}

// ---------------------------------------------------------------------------
// BN statistics
// ---------------------------------------------------------------------------
__global__ __launch_bounds__(256) void bn_stats_kernel(
    const float* __restrict__ f, float* __restrict__ acc, int N)
{
    __shared__ float s[10];
    if (threadIdx.x < 10) s[threadIdx.x] = 0.f;
    __syncthreads();
    int n = blockIdx.x * 256 + threadIdx.x;
    if (n < N) {
        #pragma unroll
        for (int k = 0; k < IN_FEAT; ++k) {
            float v = f[n * IN_FEAT + k];
            atomicAdd(&s[k], v);
            atomicAdd(&s[5 + k], v * v);
        }
    }
    __syncthreads();
    if (threadIdx.x < 10) atomicAdd(&acc[threadIdx.x], s[threadIdx.x]);
}

__global__ __launch_bounds__(256) void bn_norm_kernel(
    const float* __restrict__ f, const float* __restrict__ acc,
    const float* __restrict__ gamma, const float* __restrict__ beta,
    float* __restrict__ X0, int N)
{
    int i = blockIdx.x * 256 + threadIdx.x;
    if (i >= N * IN_FEAT) return;
    int k = i % IN_FEAT;
    float mu = acc[k] / (float)N;
    float var = acc[5 + k] / (float)N - mu * mu;
    float sc = gamma[k] / sqrtf(var + BN_EPS);
    X0[i] = (f[i] - mu) * sc + beta[k];
}

// ---------------------------------------------------------------------------
// CSR build
// ---------------------------------------------------------------------------
__global__ __launch_bounds__(256) void hist_kernel(
    const int* __restrict__ dst, int* __restrict__ counts, int E)
{
    int e = blockIdx.x * 256 + threadIdx.x;
    if (e < E) atomicAdd(&counts[dst[e]], 1);
}

__global__ __launch_bounds__(1024) void scan_kernel(
    const int* __restrict__ counts, int* __restrict__ row_off,
    float* __restrict__ deg_inv, int N)
{
    __shared__ int s[1024];
    const int CH = 30;
    int t = threadIdx.x;
    int base = t * CH;
    int loc = 0;
    for (int j = 0; j < CH; ++j) {
        int i = base + j;
        if (i < N) loc += counts[i];
    }
    s[t] = loc;
    __syncthreads();
    for (int off = 1; off < 1024; off <<= 1) {
        int v = (t >= off) ? s[t - off] : 0;
        __syncthreads();
        s[t] += v;
        __syncthreads();
    }
    int run = s[t] - loc;
    for (int j = 0; j < CH; ++j) {
        int i = base + j;
        if (i < N) {
            int cv = counts[i];
            row_off[i] = run;
            run += cv;
            deg_inv[i] = 1.0f / fmaxf((float)cv, 1.0f);
        }
    }
    if (t == 1023) row_off[N] = s[1023];
}

__global__ __launch_bounds__(256) void csr_fill_kernel(
    const int* __restrict__ dst, const int* __restrict__ src,
    const int* __restrict__ row_off, int* __restrict__ cursor,
    int* __restrict__ csr_src, int* __restrict__ csr_dst, int E)
{
    int e = blockIdx.x * 256 + threadIdx.x;
    if (e < E) {
        int d = dst[e];
        int p = atomicAdd(&cursor[d], 1);
        csr_src[row_off[d] + p] = src[e];
        csr_dst[row_off[d] + p] = d;
    }
}

// ---------------------------------------------------------------------------
// Per-layer weight prep:
//  W1p[k*C+m] = pack(bf16(W1a[k][m]-W1b[k][m]), bf16(W1b[k][m]))
//  W2p = bf16(W2) transposed [n][k] with XOR-16B swizzle, as the LDS image.
// ---------------------------------------------------------------------------
template<int F, int C>
__global__ __launch_bounds__(256) void prep_kernel(
    const float* __restrict__ W1, const float* __restrict__ W2,
    u32* __restrict__ W1p, u16* __restrict__ W2p)
{
    int i = blockIdx.x * 256 + threadIdx.x;
    if (i < F * C) {
        float wa = W1[i];
        float wb = W1[F * C + i];
        W1p[i] = (u32)f2bf(wa - wb) | ((u32)f2bf(wb) << 16);
    }
    i -= F * C;
    if (i >= 0 && i < C * C) {
        int k = i / C, n = i % C;
        int byte = ((n * C + k) * 2) ^ ((n & 7) << 4);
        *(u16*)((char*)W2p + byte) = f2bf(W2[i]);
    }
}

// ---------------------------------------------------------------------------
// Node transform: U = X @ (W1a - W1b) + b1 ; V = X @ W1b   (bf16 outputs)
// ---------------------------------------------------------------------------
template <int F, int C>
__global__ __launch_bounds__(256) void node_transform_kernel(
    const float* __restrict__ X, const u32* __restrict__ W1p,
    const float* __restrict__ b1, u16* __restrict__ U,
    u16* __restrict__ V, int N)
{
    constexpr int NS = 256 / C;
    __shared__ float xs[NS][F];
    const int n0 = blockIdx.x * NS;
    for (int i = threadIdx.x; i < NS * F; i += 256) {
        int nn = n0 + i / F;
        xs[i / F][i % F] = (nn < N) ? X[nn * F + i % F] : 0.f;
    }
    __syncthreads();
    const int m = threadIdx.x % C;
    const int ns = threadIdx.x / C;
    const int n = n0 + ns;
    if (n >= N) return;
    float au = b1[m], av = 0.f;
    #pragma unroll 4
    for (int k = 0; k < F; ++k) {
        const float xv = xs[ns][k];
        const u32 w = W1p[k * C + m];
        au += xv * bf2f((u16)(w & 0xffff));
        av += xv * bf2f((u16)(w >> 16));
    }
    U[n * C + m] = f2bf(au);
    V[n * C + m] = f2bf(av);
}

// ---------------------------------------------------------------------------
// Edge-parallel MFMA GEMM: for CSR edges [e_lo, e_hi), tile = 64 edges x C.
//   h1[e][k] = relu(U[csr_dst[e]][k] + V[csr_src[e]][k])  (bf16, LDS, swizzled)
//   H2[e][n] = bf16(relu(sum_k h1[e][k]*W2[k][n] + b2[n]))
// 16x16x32 bf16 MFMA, fp32 accum. 4 waves.
// ---------------------------------------------------------------------------
template <int C>
__global__ __launch_bounds__(256) void edge_gemm_kernel(
    const u16* __restrict__ U, const u16* __restrict__ V,
    const int* __restrict__ csr_src, const int* __restrict__ csr_dst,
    const u16* __restrict__ W2p, const float* __restrict__ b2,
    u16* __restrict__ H2, int e_lo, int e_hi)
{
    __shared__ u16 w2t[C * C];   // swizzled [n][k] bf16 (pre-baked image)
    __shared__ u16 at[64 * C];   // swizzled [e][k] bf16

    // W2 LDS image: linear copy (swizzle pre-applied by prep kernel)
    for (int i = threadIdx.x; i < C * C / 8; i += 256)
        reinterpret_cast<uint4*>(w2t)[i] = reinterpret_cast<const uint4*>(W2p)[i];

    // Stage A-tile: 4 threads per edge, KPT = C/4 features each
    constexpr int KPT = C / 4;
    const int e_loc = threadIdx.x >> 2;
    const int part  = threadIdx.x & 3;
    const int k0 = part * KPT;
    const int e_base = e_lo + blockIdx.x * 64;
    const int e = e_base + e_loc;
    const bool valid = (e < e_hi);
    const int dn = valid ? csr_dst[e] : 0;
    const int sn = valid ? csr_src[e] : 0;

    #pragma unroll
    for (int j = 0; j < KPT / 8; ++j) {
        uint4 uu = {0, 0, 0, 0}, vv = {0, 0, 0, 0};
        if (valid) {
            uu = *reinterpret_cast<const uint4*>(U + (size_t)dn * C + k0 + j * 8);
            vv = *reinterpret_cast<const uint4*>(V + (size_t)sn * C + k0 + j * 8);
        }
        u32 out[4];
        #pragma unroll
        for (int q = 0; q < 4; ++q) {
            u32 a = (&uu.x)[q], b = (&vv.x)[q];
            float lo = bf2f((u16)(a & 0xffff)) + bf2f((u16)(b & 0xffff));
            float hi = bf2f((u16)(a >> 16)) + bf2f((u16)(b >> 16));
            lo = fmaxf(lo, 0.f);
            hi = fmaxf(hi, 0.f);
            out[q] = (u32)f2bf(lo) | ((u32)f2bf(hi) << 16);
        }
        int byte = ((e_loc * C + k0 + j * 8) * 2) ^ ((e_loc & 7) << 4);
        *reinterpret_cast<uint4*>((char*)at + byte) = *reinterpret_cast<uint4*>(out);
    }
    __syncthreads();

    // MFMA: M-tiles = 4 (64 edges), N-tiles = C/16, K-steps = C/32
    constexpr int NT  = C / 16;
    constexpr int NPW = (NT >= 4) ? NT / 4 : NT;  // n-tiles per wave (2,1) / C=32: 2
    constexpr int MPW = (NT >= 4) ? 4 : 1;        // m-tiles per wave
    constexpr int KS  = C / 32;

    const int wid  = threadIdx.x >> 6;
    const int lane = threadIdx.x & 63;
    const int lrow = lane & 15;
    const int lk8  = (lane >> 4) * 8;

    f32x4 acc[MPW][NPW] = {};

    #pragma unroll
    for (int ks = 0; ks < KS; ++ks) {
        short8 afrag[MPW], bfrag[NPW];
        #pragma unroll
        for (int m = 0; m < MPW; ++m) {
            int row = ((NT >= 4) ? m : wid) * 16 + lrow;
            int byte = ((row * C + ks * 32 + lk8) * 2) ^ ((row & 7) << 4);
            afrag[m] = *reinterpret_cast<const short8*>((const char*)at + byte);
        }
        #pragma unroll
        for (int n = 0; n < NPW; ++n) {
            int col = ((NT >= 4) ? (wid * NPW + n) : n) * 16 + lrow;
            int byte = ((col * C + ks * 32 + lk8) * 2) ^ ((col & 7) << 4);
            bfrag[n] = *reinterpret_cast<const short8*>((const char*)w2t + byte);
        }
        #pragma unroll
        for (int m = 0; m < MPW; ++m)
            #pragma unroll
            for (int n = 0; n < NPW; ++n)
                acc[m][n] = __builtin_amdgcn_mfma_f32_16x16x32_bf16(
                    afrag[m], bfrag[n], acc[m][n], 0, 0, 0);
    }

    // Epilogue: +b2, relu, bf16, write H2 (CSR-local index)
    #pragma unroll
    for (int m = 0; m < MPW; ++m) {
        int row0 = ((NT >= 4) ? m : wid) * 16 + (lane >> 4) * 4;
        #pragma unroll
        for (int n = 0; n < NPW; ++n) {
            int col = ((NT >= 4) ? (wid * NPW + n) : n) * 16 + lrow;
            float bb = b2[col];
            #pragma unroll
            for (int j = 0; j < 4; ++j) {
                int erow = row0 + j;
                int eg = e_base + erow;
                if (eg < e_hi) {
                    float z = fmaxf(acc[m][n][j] + bb, 0.f);
                    H2[(size_t)(eg - e_lo) * C + col] = f2bf(z);
                }
            }
        }
    }
}

// ---------------------------------------------------------------------------
// CSR segment-sum of H2 chunk into Xout (fp32). flags: 1=first chunk, 2=last.
// ---------------------------------------------------------------------------
template <int C>
__global__ __launch_bounds__(256) void seg_sum_kernel(
    const u16* __restrict__ H2, const int* __restrict__ row_off,
    const float* __restrict__ deg_inv, float* __restrict__ Xout,
    int e_lo, int e_hi, int flags, int N)
{
    const int wid = threadIdx.x >> 6;
    const int lane = threadIdx.x & 63;
    if constexpr (C == 128) {
        int node = blockIdx.x * 4 + wid;
        if (node >= N) return;
        int rs = max(row_off[node], e_lo), re = min(row_off[node + 1], e_hi);
        float a0 = 0.f, a1 = 0.f;
        for (int e = rs; e < re; ++e) {
            u32 w = *reinterpret_cast<const u32*>(H2 + (size_t)(e - e_lo) * 128 + lane * 2);
            a0 += bf2f((u16)(w & 0xffff));
            a1 += bf2f((u16)(w >> 16));
        }
        size_t o = (size_t)node * 128 + lane * 2;
        float p0 = (flags & 1) ? 0.f : Xout[o];
        float p1 = (flags & 1) ? 0.f : Xout[o + 1];
        p0 += a0; p1 += a1;
        if (flags & 2) { float d = deg_inv[node]; p0 *= d; p1 *= d; }
        Xout[o] = p0; Xout[o + 1] = p1;
    } else if constexpr (C == 64) {
        int node = blockIdx.x * 4 + wid;
        if (node >= N) return;
        int rs = max(row_off[node], e_lo), re = min(row_off[node + 1], e_hi);
        float a0 = 0.f;
        for (int e = rs; e < re; ++e)
            a0 += bf2f(H2[(size_t)(e - e_lo) * 64 + lane]);
        size_t o = (size_t)node * 64 + lane;
        float p0 = (flags & 1) ? 0.f : Xout[o];
        p0 += a0;
        if (flags & 2) p0 *= deg_inv[node];
        Xout[o] = p0;
    } else {  // C == 32
        int node = blockIdx.x * 8 + wid * 2 + (lane >> 5);
        int col = lane & 31;
        if (node >= N) return;
        int rs = max(row_off[node], e_lo), re = min(row_off[node + 1], e_hi);
        float a0 = 0.f;
        for (int e = rs; e < re; ++e)
            a0 += bf2f(H2[(size_t)(e - e_lo) * 32 + col]);
        size_t o = (size_t)node * 32 + col;
        float p0 = (flags & 1) ? 0.f : Xout[o];
        p0 += a0;
        if (flags & 2) p0 *= deg_inv[node];
        Xout[o] = p0;
    }
}

// ---------------------------------------------------------------------------
// Centroid distances
// ---------------------------------------------------------------------------
__global__ __launch_bounds__(256) void dist_kernel(
    const float* __restrict__ X, const float* __restrict__ centroids,
    float* __restrict__ dist, int N)
{
    __shared__ float centT[128 * NUM_CENTROID];
    __shared__ float xs[4][128];
    for (int i = threadIdx.x; i < NUM_CENTROID * 128; i += 256) {
        int c = i / 128, d = i % 128;
        centT[d * NUM_CENTROID + c] = centroids[i];
    }
    __syncthreads();
    const int wid = threadIdx.x >> 6;
    const int lane = threadIdx.x & 63;
    const int n = blockIdx.x * 4 + wid;
    if (n >= N) return;
    xs[wid][lane] = X[n * 128 + lane];
    xs[wid][lane + 64] = X[n * 128 + lane + 64];
    __builtin_amdgcn_wave_barrier();
    float a0 = 0.f, a1 = 0.f;
    #pragma unroll 4
    for (int d = 0; d < 128; ++d) {
        const float xv = xs[wid][d];
        const float d0 = xv - centT[d * NUM_CENTROID + lane];
        a0 += d0 * d0;
        if (lane < NUM_CENTROID - 64) {
            const float d1 = xv - centT[d * NUM_CENTROID + lane + 64];
            a1 += d1 * d1;
        }
    }
    dist[n * NUM_CENTROID + lane] = sqrtf(a0 + 1e-12f);
    if (lane < NUM_CENTROID - 64)
        dist[n * NUM_CENTROID + lane + 64] = sqrtf(a1 + 1e-12f);
}

// ---------------------------------------------------------------------------
// Per-graph pooling + FC
// ---------------------------------------------------------------------------
__global__ __launch_bounds__(128) void pool_fc_kernel(
    const float* __restrict__ dist, const int* __restrict__ gid,
    const float* __restrict__ fc_w, const float* __restrict__ fc_b,
    float* __restrict__ out, int N)
{
    __shared__ float pooled[NUM_CENTROID];
    const int g = blockIdx.x;
    const int t = threadIdx.x;

    int lo = 0, hi = N;
    while (lo < hi) { int mid = (lo + hi) >> 1; if (gid[mid] < g) lo = mid + 1; else hi = mid; }
    const int start = lo;
    hi = N;
    while (lo < hi) { int mid = (lo + hi) >> 1; if (gid[mid] < g + 1) lo = mid + 1; else hi = mid; }
    const int end = lo;

    if (t < NUM_CENTROID) {
        float s = 0.f;
        for (int n = start; n < end; ++n) s += dist[n * NUM_CENTROID + t];
        pooled[t] = s / fmaxf((float)(end - start), 1.0f);
    }
    __syncthreads();
    if (t < 2) {
        float o = fc_b[t];
        for (int c = 0; c < NUM_CENTROID; ++c) o += pooled[c] * fc_w[c * 2 + t];
        out[g * 2 + t] = o;
    }
}

// ---------------------------------------------------------------------------
// Host-side per-layer driver
// ---------------------------------------------------------------------------
template <int F, int C>
static void run_layer(const float* Xin, float* Xout,
                      const float* W1, const float* b1,
                      const float* W2, const float* b2,
                      u16* Ubf, u16* Vbf, u32* W1p, u16* W2p, u16* H2,
                      const int* csr_src, const int* csr_dst,
                      const int* row_off, const float* deg_inv,
                      int chunk, hipStream_t stream)
{
    prep_kernel<F, C><<<(F * C + C * C + 255) / 256, 256, 0, stream>>>(W1, W2, W1p, W2p);
    constexpr int NS = 256 / C;
    node_transform_kernel<F, C><<<(N_NODES + NS - 1) / NS, 256, 0, stream>>>(
        Xin, W1p, b1, Ubf, Vbf, N_NODES);
    for (int lo = 0; lo < N_EDGES; lo += chunk) {
        int hi = (lo + chunk < N_EDGES) ? lo + chunk : N_EDGES;
        int nb = (hi - lo + 63) / 64;
        edge_gemm_kernel<C><<<nb, 256, 0, stream>>>(
            Ubf, Vbf, csr_src, csr_dst, W2p, b2, H2, lo, hi);
        int flags = (lo == 0 ? 1 : 0) | (hi == N_EDGES ? 2 : 0);
        if constexpr (C == 32)
            seg_sum_kernel<C><<<(N_NODES + 7) / 8, 256, 0, stream>>>(
                H2, row_off, deg_inv, Xout, lo, hi, flags, N_NODES);
        else
            seg_sum_kernel<C><<<(N_NODES + 3) / 4, 256, 0, stream>>>(
                H2, row_off, deg_inv, Xout, lo, hi, flags, N_NODES);
    }
}

extern "C" void kernel_launch(void* const* d_in, const int* in_sizes, int n_in,
                              void* d_out, int out_size, void* d_ws, size_t ws_size,
                              hipStream_t stream) {
    const float* features = (const float*)d_in[0];
    const int*   src      = (const int*)d_in[1];
    const int*   dst      = (const int*)d_in[2];
    const int*   gid      = (const int*)d_in[3];
    const float* gamma    = (const float*)d_in[4];
    const float* beta     = (const float*)d_in[5];
    const float *W1[6], *b1[6], *W2[6], *b2[6];
    for (int i = 0; i < 6; ++i) {
        W1[i] = (const float*)d_in[6 + 4 * i];
        b1[i] = (const float*)d_in[7 + 4 * i];
        W2[i] = (const float*)d_in[8 + 4 * i];
        b2[i] = (const float*)d_in[9 + 4 * i];
    }
    const float* centroids = (const float*)d_in[30];
    const float* fc_w      = (const float*)d_in[31];
    const float* fc_b      = (const float*)d_in[32];

    const int N = N_NODES, E = N_EDGES;

    char* p = (char*)d_ws;
    size_t off = 0;
    auto alloc = [&](size_t bytes) {
        void* r = p + off;
        off += (bytes + 255) & ~(size_t)255;
        return r;
    };
    float* X0      = (float*)alloc((size_t)N * 128 * 4);
    float* X1      = (float*)alloc((size_t)N * 128 * 4);
    u16*   Ubf     = (u16*)alloc((size_t)N * 128 * 2);
    u16*   Vbf     = (u16*)alloc((size_t)N * 128 * 2);
    float* distb   = (float*)alloc((size_t)N * NUM_CENTROID * 4);
    int*   row_off = (int*)alloc((size_t)(N + 1) * 4);
    int*   csr_src = (int*)alloc((size_t)E * 4);
    int*   csr_dst = (int*)alloc((size_t)E * 4);
    float* deg_inv = (float*)alloc((size_t)N * 4);
    u32*   W1p     = (u32*)alloc((size_t)128 * 128 * 4);
    u16*   W2p     = (u16*)alloc((size_t)128 * 128 * 2);
    char*  zero0   = (char*)(p + off);
    int*   counts  = (int*)alloc((size_t)N * 4);
    int*   cursor  = (int*)alloc((size_t)N * 4);
    float* bnacc   = (float*)alloc(64);
    size_t zbytes  = (size_t)((char*)(p + off) - zero0);

    // H2 chunk buffer: everything that remains (worst case C=128 -> 256 B/edge)
    u16* H2 = (u16*)(p + off);
    size_t avail = (ws_size > off) ? (ws_size - off) : 0;
    long long maxe = (long long)(avail / 256);
    int chunk;
    if (maxe >= E) {
        chunk = E;
    } else {
        if (maxe < 64) maxe = 64;  // trust ws is at least minimally sized
        int nc = (int)((E + maxe - 1) / maxe);
        chunk = (E + nc - 1) / nc;
        chunk = (chunk + 63) & ~63;
    }

    hipMemsetAsync(zero0, 0, zbytes, stream);

    bn_stats_kernel<<<(N + 255) / 256, 256, 0, stream>>>(features, bnacc, N);
    hist_kernel<<<(E + 255) / 256, 256, 0, stream>>>(dst, counts, E);
    scan_kernel<<<1, 1024, 0, stream>>>(counts, row_off, deg_inv, N);
    csr_fill_kernel<<<(E + 255) / 256, 256, 0, stream>>>(dst, src, row_off, cursor, csr_src, csr_dst, E);
    bn_norm_kernel<<<(N * IN_FEAT + 255) / 256, 256, 0, stream>>>(features, bnacc, gamma, beta, X0, N);

    run_layer<5, 32>(X0, X1, W1[0], b1[0], W2[0], b2[0], Ubf, Vbf, W1p, W2p, H2,
                     csr_src, csr_dst, row_off, deg_inv, chunk, stream);
    run_layer<32, 32>(X1, X0, W1[1], b1[1], W2[1], b2[1], Ubf, Vbf, W1p, W2p, H2,
                      csr_src, csr_dst, row_off, deg_inv, chunk, stream);
    run_layer<32, 64>(X0, X1, W1[2], b1[2], W2[2], b2[2], Ubf, Vbf, W1p, W2p, H2,
                      csr_src, csr_dst, row_off, deg_inv, chunk, stream);
    run_layer<64, 64>(X1, X0, W1[3], b1[3], W2[3], b2[3], Ubf, Vbf, W1p, W2p, H2,
                      csr_src, csr_dst, row_off, deg_inv, chunk, stream);
    run_layer<64, 128>(X0, X1, W1[4], b1[4], W2[4], b2[4], Ubf, Vbf, W1p, W2p, H2,
                       csr_src, csr_dst, row_off, deg_inv, chunk, stream);
    run_layer<128, 128>(X1, X0, W1[5], b1[5], W2[5], b2[5], Ubf, Vbf, W1p, W2p, H2,
                        csr_src, csr_dst, row_off, deg_inv, chunk, stream);

    dist_kernel<<<(N + 3) / 4, 256, 0, stream>>>(X0, centroids, distb, N);
    pool_fc_kernel<<<N_GRAPHS, 128, 0, stream>>>(distb, gid, fc_w, fc_b, (float*)d_out, N);
}

// Round 3
// 670.543 us; speedup vs baseline: 4.2509x; 1.5615x over previous
//
#include <hip/hip_runtime.h>
#include <hip/hip_bf16.h>

// ---------------------------------------------------------------------------
// HyperbolicGNN: BN -> 6x EdgeConv -> centroid dist -> pool -> FC
// All GEMM-shaped work on bf16 MFMA (16x16x32), fp32 accum.
// EdgeConv: U=X@(W1a-W1b)+b1, V=X@W1b (node MFMA GEMM);
//   edge_agg: h1=relu(U[dst]+V[src]) -> MFMA @W2 -> relu -> LDS tile ->
//   segmented scan over CSR dst -> fp32 atomicAdd into Xout (unscaled).
// deg_inv deferred into the NEXT consumer's A-staging.
// dist: |x|^2 - 2 x.c + |c|^2 via MFMA, consistent bf16 rounding.
// ---------------------------------------------------------------------------
#define N_NODES 30000
#define N_EDGES 480000
#define N_GRAPHS 128
#define IN_FEAT 5
#define NUM_CENTROID 100
#define BN_EPS 1e-5f

typedef unsigned int u32;
typedef unsigned short u16;

using short8 = __attribute__((ext_vector_type(8))) short;
using f32x4  = __attribute__((ext_vector_type(4))) float;

__device__ __forceinline__ u16 f2bf(float x) {
    u32 u = __builtin_bit_cast(u32, x);
    u32 r = (u + 0x7FFFu + ((u >> 16) & 1u)) >> 16;
    return (u16)r;
}
__device__ __forceinline__ float bf2f(u16 h) {
    u32 u = ((u32)h) << 16;
    return __builtin_bit_cast(float, u);
}
__device__ __forceinline__ u32 pack2(float lo, float hi) {
    return (u32)f2bf(lo) | ((u32)f2bf(hi) << 16);
}

// ---------------------------------------------------------------------------
// BN statistics + apply
// ---------------------------------------------------------------------------
__global__ __launch_bounds__(256) void bn_stats_kernel(
    const float* __restrict__ f, float* __restrict__ acc, int N)
{
    __shared__ float s[10];
    if (threadIdx.x < 10) s[threadIdx.x] = 0.f;
    __syncthreads();
    int n = blockIdx.x * 256 + threadIdx.x;
    if (n < N) {
        #pragma unroll
        for (int k = 0; k < IN_FEAT; ++k) {
            float v = f[n * IN_FEAT + k];
            atomicAdd(&s[k], v);
            atomicAdd(&s[5 + k], v * v);
        }
    }
    __syncthreads();
    if (threadIdx.x < 10) atomicAdd(&acc[threadIdx.x], s[threadIdx.x]);
}

__global__ __launch_bounds__(256) void bn_norm_kernel(
    const float* __restrict__ f, const float* __restrict__ acc,
    const float* __restrict__ gamma, const float* __restrict__ beta,
    float* __restrict__ X0, int N)
{
    int i = blockIdx.x * 256 + threadIdx.x;
    if (i >= N * IN_FEAT) return;
    int k = i % IN_FEAT;
    float mu = acc[k] / (float)N;
    float var = acc[5 + k] / (float)N - mu * mu;
    float sc = gamma[k] / sqrtf(var + BN_EPS);
    X0[i] = (f[i] - mu) * sc + beta[k];
}

// ---------------------------------------------------------------------------
// CSR build
// ---------------------------------------------------------------------------
__global__ __launch_bounds__(256) void hist_kernel(
    const int* __restrict__ dst, int* __restrict__ counts, int E)
{
    int e = blockIdx.x * 256 + threadIdx.x;
    if (e < E) atomicAdd(&counts[dst[e]], 1);
}

__global__ __launch_bounds__(1024) void scan_kernel(
    const int* __restrict__ counts, int* __restrict__ row_off,
    float* __restrict__ deg_inv, int N)
{
    __shared__ int s[1024];
    const int CH = 30;
    int t = threadIdx.x;
    int base = t * CH;
    int loc = 0;
    for (int j = 0; j < CH; ++j) {
        int i = base + j;
        if (i < N) loc += counts[i];
    }
    s[t] = loc;
    __syncthreads();
    for (int off = 1; off < 1024; off <<= 1) {
        int v = (t >= off) ? s[t - off] : 0;
        __syncthreads();
        s[t] += v;
        __syncthreads();
    }
    int run = s[t] - loc;
    for (int j = 0; j < CH; ++j) {
        int i = base + j;
        if (i < N) {
            int cv = counts[i];
            row_off[i] = run;
            run += cv;
            deg_inv[i] = 1.0f / fmaxf((float)cv, 1.0f);
        }
    }
    if (t == 1023) row_off[N] = s[1023];
}

__global__ __launch_bounds__(256) void csr_fill_kernel(
    const int* __restrict__ dst, const int* __restrict__ src,
    const int* __restrict__ row_off, int* __restrict__ cursor,
    int* __restrict__ csr_src, int* __restrict__ csr_dst, int E)
{
    int e = blockIdx.x * 256 + threadIdx.x;
    if (e < E) {
        int d = dst[e];
        int p = atomicAdd(&cursor[d], 1);
        csr_src[row_off[d] + p] = src[e];
        csr_dst[row_off[d] + p] = d;
    }
}

// ---------------------------------------------------------------------------
// Mega-prep: all weight images (bf16, [n_out][k] k-major, XOR-16B swizzled),
// centroid image + |c|^2.
// ---------------------------------------------------------------------------
struct PrepArgs {
    const float* w1[6];
    const float* w2[6];
    const float* cent;
    u16* w1img;
    u16* w2img;
    u16* centimg;
    float* csq;
};

__constant__ __device__ const int LFIN[6] = {5, 32, 32, 64, 64, 128};
__constant__ __device__ const int LKD[6]  = {32, 32, 32, 64, 64, 128};
__constant__ __device__ const int LCD[6]  = {32, 32, 64, 64, 128, 128};
__constant__ __device__ const int W1OFF[6] = {0, 2048, 4096, 8192, 16384, 32768};
__constant__ __device__ const int W2OFF[6] = {0, 1024, 2048, 6144, 10240, 26624};
#define W1TOT 65536
#define W2TOT 43008
#define CTOT  14336  // 112*128
#define PREP_TOT (W1TOT + W2TOT + CTOT + 112)

__global__ __launch_bounds__(256) void megaprep_kernel(PrepArgs a)
{
    int gid = blockIdx.x * 256 + threadIdx.x;
    if (gid < W1TOT) {
        int l = 0;
        #pragma unroll
        for (int i = 1; i < 6; ++i) if (gid >= W1OFF[i]) l = i;
        int local = gid - W1OFF[l];
        int K = LKD[l], C = LCD[l], F = LFIN[l];
        int n = local / K, k = local % K;
        float v = 0.f;
        if (k < F) {
            if (n < C) v = a.w1[l][k * C + n] - a.w1[l][(F + k) * C + n];
            else       v = a.w1[l][(F + k) * C + (n - C)];
        }
        int byte = (local * 2) ^ ((n & 7) << 4);
        *(u16*)((char*)a.w1img + (size_t)W1OFF[l] * 2 + byte) = f2bf(v);
        return;
    }
    int g2 = gid - W1TOT;
    if (g2 < W2TOT) {
        int l = 0;
        #pragma unroll
        for (int i = 1; i < 6; ++i) if (g2 >= W2OFF[i]) l = i;
        int local = g2 - W2OFF[l];
        int C = LCD[l];
        int n = local / C, k = local % C;
        float v = a.w2[l][k * C + n];
        int byte = (local * 2) ^ ((n & 7) << 4);
        *(u16*)((char*)a.w2img + (size_t)W2OFF[l] * 2 + byte) = f2bf(v);
        return;
    }
    int g3 = g2 - W2TOT;
    if (g3 < CTOT) {
        int c = g3 / 128, d = g3 % 128;
        float v = (c < NUM_CENTROID) ? a.cent[c * 128 + d] : 0.f;
        int byte = (g3 * 2) ^ ((c & 7) << 4);
        *(u16*)((char*)a.centimg + byte) = f2bf(v);
        return;
    }
    int c = g3 - CTOT;
    if (c < 112) {
        float s = 0.f;
        if (c < NUM_CENTROID) {
            for (int d = 0; d < 128; ++d) {
                float cv = bf2f(f2bf(a.cent[c * 128 + d]));
                s += cv * cv;
            }
        }
        a.csq[c] = s;
    }
}

// ---------------------------------------------------------------------------
// Node MFMA GEMM: [32 nodes] x [2C cols].
//   cols < C  -> U = (x*scale) @ (W1a-W1b) + b1 ;  cols >= C -> V = (x*scale) @ W1b
// ---------------------------------------------------------------------------
template <int FIN, int K, int C>
__global__ __launch_bounds__(256) void node_mfma_kernel(
    const float* __restrict__ Xin, const float* __restrict__ scale,
    const u16* __restrict__ w1img, const float* __restrict__ b1,
    u16* __restrict__ U, u16* __restrict__ V, int N)
{
    constexpr int COLS = 2 * C;
    __shared__ u16 wt[COLS * K];
    __shared__ u16 xt[32 * K];

    for (int i = threadIdx.x; i < COLS * K / 8; i += 256)
        reinterpret_cast<uint4*>(wt)[i] = reinterpret_cast<const uint4*>(w1img)[i];

    constexpr int DPT = K / 8;
    const int nl = threadIdx.x >> 3;
    const int part = threadIdx.x & 7;
    const int n = blockIdx.x * 32 + nl;
    const int k0 = part * DPT;
    const bool vld = (n < N);
    float s = 1.f;
    if (vld && scale) s = scale[n];

    float xv[DPT];
    if constexpr (FIN == K) {
        #pragma unroll
        for (int j4 = 0; j4 < DPT / 4; ++j4) {
            float4 f4 = {0, 0, 0, 0};
            if (vld) f4 = *reinterpret_cast<const float4*>(Xin + (size_t)n * FIN + k0 + j4 * 4);
            xv[j4 * 4 + 0] = f4.x * s; xv[j4 * 4 + 1] = f4.y * s;
            xv[j4 * 4 + 2] = f4.z * s; xv[j4 * 4 + 3] = f4.w * s;
        }
    } else {
        #pragma unroll
        for (int j = 0; j < DPT; ++j) {
            int k = k0 + j;
            xv[j] = (vld && k < FIN) ? Xin[(size_t)n * FIN + k] * s : 0.f;
        }
    }

    if constexpr (DPT == 4) {
        u32 o[2];
        o[0] = pack2(xv[0], xv[1]);
        o[1] = pack2(xv[2], xv[3]);
        int byte = ((nl * K + k0) * 2) ^ ((nl & 7) << 4);
        *reinterpret_cast<uint2*>((char*)xt + byte) = *reinterpret_cast<uint2*>(o);
    } else {
        #pragma unroll
        for (int j8 = 0; j8 < DPT / 8; ++j8) {
            u32 o[4];
            #pragma unroll
            for (int q = 0; q < 4; ++q)
                o[q] = pack2(xv[j8 * 8 + q * 2], xv[j8 * 8 + q * 2 + 1]);
            int byte = ((nl * K + k0 + j8 * 8) * 2) ^ ((nl & 7) << 4);
            *reinterpret_cast<uint4*>((char*)xt + byte) = *reinterpret_cast<uint4*>(o);
        }
    }
    __syncthreads();

    constexpr int NT = COLS / 16;
    constexpr int NPW = NT / 4;   // 1, 2, 4
    constexpr int KS = K / 32;

    const int wid = threadIdx.x >> 6;
    const int lane = threadIdx.x & 63;
    const int lrow = lane & 15;
    const int lk8 = (lane >> 4) * 8;

    f32x4 acc[2][NPW] = {};

    #pragma unroll
    for (int ks = 0; ks < KS; ++ks) {
        short8 afrag[2];
        #pragma unroll
        for (int m = 0; m < 2; ++m) {
            int row = m * 16 + lrow;
            int byte = ((row * K + ks * 32 + lk8) * 2) ^ ((row & 7) << 4);
            afrag[m] = *reinterpret_cast<const short8*>((const char*)xt + byte);
        }
        #pragma unroll
        for (int nn = 0; nn < NPW; ++nn) {
            int colr = (wid * NPW + nn) * 16 + lrow;
            int byte = ((colr * K + ks * 32 + lk8) * 2) ^ ((colr & 7) << 4);
            short8 bfrag = *reinterpret_cast<const short8*>((const char*)wt + byte);
            #pragma unroll
            for (int m = 0; m < 2; ++m)
                acc[m][nn] = __builtin_amdgcn_mfma_f32_16x16x32_bf16(
                    afrag[m], bfrag, acc[m][nn], 0, 0, 0);
        }
    }

    #pragma unroll
    for (int nn = 0; nn < NPW; ++nn) {
        int colr = (wid * NPW + nn) * 16 + lrow;
        float bias = (colr < C) ? b1[colr] : 0.f;
        #pragma unroll
        for (int m = 0; m < 2; ++m) {
            #pragma unroll
            for (int j = 0; j < 4; ++j) {
                int row = m * 16 + (lane >> 4) * 4 + j;
                int node = blockIdx.x * 32 + row;
                if (node < N) {
                    float z = acc[m][nn][j] + bias;
                    if (colr < C) U[(size_t)node * C + colr] = f2bf(z);
                    else          V[(size_t)node * C + colr - C] = f2bf(z);
                }
            }
        }
    }
}

// ---------------------------------------------------------------------------
// Fused edge GEMM + segmented reduction (atomicAdd into unscaled Xout).
// ---------------------------------------------------------------------------
template <int C>
__global__ __launch_bounds__(256) void edge_agg_kernel(
    const u16* __restrict__ U, const u16* __restrict__ V,
    const int* __restrict__ csr_src, const int* __restrict__ csr_dst,
    const u16* __restrict__ w2img, const float* __restrict__ b2,
    float* __restrict__ Xout, int E)
{
    __shared__ u16 w2t[C * C];
    __shared__ u16 at[64 * (C + 8)];
    __shared__ int dstid[64];

    for (int i = threadIdx.x; i < C * C / 8; i += 256)
        reinterpret_cast<uint4*>(w2t)[i] = reinterpret_cast<const uint4*>(w2img)[i];

    constexpr int KPT = C / 4;
    const int e_loc = threadIdx.x >> 2;
    const int part = threadIdx.x & 3;
    const int k0 = part * KPT;
    const int e = blockIdx.x * 64 + e_loc;
    const bool valid = (e < E);
    const int dn = valid ? csr_dst[e] : 0;
    const int sn = valid ? csr_src[e] : 0;
    if (part == 0) dstid[e_loc] = valid ? dn : -1;

    #pragma unroll
    for (int j = 0; j < KPT / 8; ++j) {
        uint4 uu = {0, 0, 0, 0}, vv = {0, 0, 0, 0};
        if (valid) {
            uu = *reinterpret_cast<const uint4*>(U + (size_t)dn * C + k0 + j * 8);
            vv = *reinterpret_cast<const uint4*>(V + (size_t)sn * C + k0 + j * 8);
        }
        u32 out[4];
        #pragma unroll
        for (int q = 0; q < 4; ++q) {
            u32 aa = (&uu.x)[q], bb = (&vv.x)[q];
            float lo = bf2f((u16)(aa & 0xffff)) + bf2f((u16)(bb & 0xffff));
            float hi = bf2f((u16)(aa >> 16)) + bf2f((u16)(bb >> 16));
            out[q] = pack2(fmaxf(lo, 0.f), fmaxf(hi, 0.f));
        }
        int byte = ((e_loc * C + k0 + j * 8) * 2) ^ ((e_loc & 7) << 4);
        *reinterpret_cast<uint4*>((char*)at + byte) = *reinterpret_cast<uint4*>(out);
    }
    __syncthreads();

    constexpr int NT = C / 16;
    constexpr int NPW = (NT >= 4) ? NT / 4 : NT;
    constexpr int MPW = (NT >= 4) ? 4 : 1;
    constexpr int KS = C / 32;

    const int wid = threadIdx.x >> 6;
    const int lane = threadIdx.x & 63;
    const int lrow = lane & 15;
    const int lk8 = (lane >> 4) * 8;

    f32x4 acc[MPW][NPW] = {};

    #pragma unroll
    for (int ks = 0; ks < KS; ++ks) {
        short8 afrag[MPW], bfrag[NPW];
        #pragma unroll
        for (int m = 0; m < MPW; ++m) {
            int row = ((NT >= 4) ? m : wid) * 16 + lrow;
            int byte = ((row * C + ks * 32 + lk8) * 2) ^ ((row & 7) << 4);
            afrag[m] = *reinterpret_cast<const short8*>((const char*)at + byte);
        }
        #pragma unroll
        for (int n = 0; n < NPW; ++n) {
            int col = ((NT >= 4) ? (wid * NPW + n) : n) * 16 + lrow;
            int byte = ((col * C + ks * 32 + lk8) * 2) ^ ((col & 7) << 4);
            bfrag[n] = *reinterpret_cast<const short8*>((const char*)w2t + byte);
        }
        #pragma unroll
        for (int m = 0; m < MPW; ++m)
            #pragma unroll
            for (int n = 0; n < NPW; ++n)
                acc[m][n] = __builtin_amdgcn_mfma_f32_16x16x32_bf16(
                    afrag[m], bfrag[n], acc[m][n], 0, 0, 0);
    }
    __syncthreads();

    #pragma unroll
    for (int m = 0; m < MPW; ++m) {
        #pragma unroll
        for (int n = 0; n < NPW; ++n) {
            int col = ((NT >= 4) ? (wid * NPW + n) : n) * 16 + lrow;
            float bb = b2[col];
            #pragma unroll
            for (int j = 0; j < 4; ++j) {
                int row = ((NT >= 4) ? m : wid) * 16 + (lane >> 4) * 4 + j;
                at[row * (C + 8) + col] = f2bf(fmaxf(acc[m][n][j] + bb, 0.f));
            }
        }
    }
    __syncthreads();

    constexpr int EPS = C / 4;
    const int col = threadIdx.x & (C - 1);
    const int e0 = (threadIdx.x / C) * EPS;
    float sum = 0.f;
    int cur = dstid[e0];
    for (int ee = e0; ee < e0 + EPS; ++ee) {
        int d = dstid[ee];
        if (d != cur) {
            if (cur >= 0) atomicAdd(&Xout[(size_t)cur * C + col], sum);
            sum = 0.f;
            cur = d;
        }
        sum += bf2f(at[ee * (C + 8) + col]);
    }
    if (cur >= 0) atomicAdd(&Xout[(size_t)cur * C + col], sum);
}

// ---------------------------------------------------------------------------
// Centroid distances via MFMA: dist^2 = |x|^2 - 2 x.c + |c|^2
// ---------------------------------------------------------------------------
__global__ __launch_bounds__(256) void dist_mfma_kernel(
    const float* __restrict__ X, const float* __restrict__ scale,
    const u16* __restrict__ centimg, const float* __restrict__ csq,
    float* __restrict__ dist, int N)
{
    __shared__ u16 ct[112 * 128];
    __shared__ u16 xt[64 * 128];
    __shared__ float xsqp[64][4];
    __shared__ float csqs[112];

    for (int i = threadIdx.x; i < 112 * 128 / 8; i += 256)
        reinterpret_cast<uint4*>(ct)[i] = reinterpret_cast<const uint4*>(centimg)[i];
    if (threadIdx.x < 112) csqs[threadIdx.x] = csq[threadIdx.x];

    const int nl = threadIdx.x >> 2;
    const int part = threadIdx.x & 3;
    const int n = blockIdx.x * 64 + nl;
    const int k0 = part * 32;
    const bool vld = (n < N);
    const float s = vld ? scale[n] : 0.f;

    float ss = 0.f;
    #pragma unroll
    for (int j8 = 0; j8 < 4; ++j8) {
        float4 f0 = {0, 0, 0, 0}, f1 = {0, 0, 0, 0};
        if (vld) {
            f0 = *reinterpret_cast<const float4*>(X + (size_t)n * 128 + k0 + j8 * 8);
            f1 = *reinterpret_cast<const float4*>(X + (size_t)n * 128 + k0 + j8 * 8 + 4);
        }
        float xv[8] = {f0.x * s, f0.y * s, f0.z * s, f0.w * s,
                       f1.x * s, f1.y * s, f1.z * s, f1.w * s};
        u32 o[4];
        #pragma unroll
        for (int q = 0; q < 4; ++q) {
            float lo = bf2f(f2bf(xv[q * 2]));
            float hi = bf2f(f2bf(xv[q * 2 + 1]));
            ss += lo * lo + hi * hi;
            o[q] = pack2(xv[q * 2], xv[q * 2 + 1]);
        }
        int byte = ((nl * 128 + k0 + j8 * 8) * 2) ^ ((nl & 7) << 4);
        *reinterpret_cast<uint4*>((char*)xt + byte) = *reinterpret_cast<uint4*>(o);
    }
    xsqp[nl][part] = ss;
    __syncthreads();

    const int wid = threadIdx.x >> 6;
    const int lane = threadIdx.x & 63;
    const int lrow = lane & 15;
    const int lk8 = (lane >> 4) * 8;

    f32x4 acc[7] = {};
    #pragma unroll
    for (int ks = 0; ks < 4; ++ks) {
        int row = wid * 16 + lrow;
        int byte = ((row * 128 + ks * 32 + lk8) * 2) ^ ((row & 7) << 4);
        short8 afrag = *reinterpret_cast<const short8*>((const char*)xt + byte);
        #pragma unroll
        for (int nn = 0; nn < 7; ++nn) {
            int colr = nn * 16 + lrow;
            int bb = ((colr * 128 + ks * 32 + lk8) * 2) ^ ((colr & 7) << 4);
            short8 bfrag = *reinterpret_cast<const short8*>((const char*)ct + bb);
            acc[nn] = __builtin_amdgcn_mfma_f32_16x16x32_bf16(afrag, bfrag, acc[nn], 0, 0, 0);
        }
    }

    float xs[4];
    #pragma unroll
    for (int j = 0; j < 4; ++j) {
        int row = wid * 16 + (lane >> 4) * 4 + j;
        xs[j] = xsqp[row][0] + xsqp[row][1] + xsqp[row][2] + xsqp[row][3];
    }
    #pragma unroll
    for (int nn = 0; nn < 7; ++nn) {
        int colr = nn * 16 + lrow;
        if (colr < NUM_CENTROID) {
            float cq = csqs[colr];
            #pragma unroll
            for (int j = 0; j < 4; ++j) {
                int row = wid * 16 + (lane >> 4) * 4 + j;
                int node = blockIdx.x * 64 + row;
                if (node < N) {
                    float v = xs[j] - 2.f * acc[nn][j] + cq;
                    dist[(size_t)node * NUM_CENTROID + colr] = sqrtf(fmaxf(v, 0.f) + 1e-12f);
                }
            }
        }
    }
}

// ---------------------------------------------------------------------------
// Per-graph pooling + FC
// ---------------------------------------------------------------------------
__global__ __launch_bounds__(128) void pool_fc_kernel(
    const float* __restrict__ dist, const int* __restrict__ gid,
    const float* __restrict__ fc_w, const float* __restrict__ fc_b,
    float* __restrict__ out, int N)
{
    __shared__ float pooled[NUM_CENTROID];
    const int g = blockIdx.x;
    const int t = threadIdx.x;

    int lo = 0, hi = N;
    while (lo < hi) { int mid = (lo + hi) >> 1; if (gid[mid] < g) lo = mid + 1; else hi = mid; }
    const int start = lo;
    hi = N;
    while (lo < hi) { int mid = (lo + hi) >> 1; if (gid[mid] < g + 1) lo = mid + 1; else hi = mid; }
    const int end = lo;

    if (t < NUM_CENTROID) {
        float s = 0.f;
        for (int n = start; n < end; ++n) s += dist[(size_t)n * NUM_CENTROID + t];
        pooled[t] = s / fmaxf((float)(end - start), 1.0f);
    }
    __syncthreads();
    if (t < 2) {
        float o = fc_b[t];
        for (int c = 0; c < NUM_CENTROID; ++c) o += pooled[c] * fc_w[c * 2 + t];
        out[g * 2 + t] = o;
    }
}

// ---------------------------------------------------------------------------
// Host launch
// ---------------------------------------------------------------------------
static const int W1OFF_H[6] = {0, 2048, 4096, 8192, 16384, 32768};
static const int W2OFF_H[6] = {0, 1024, 2048, 6144, 10240, 26624};

extern "C" void kernel_launch(void* const* d_in, const int* in_sizes, int n_in,
                              void* d_out, int out_size, void* d_ws, size_t ws_size,
                              hipStream_t stream) {
    const float* features = (const float*)d_in[0];
    const int*   src      = (const int*)d_in[1];
    const int*   dst      = (const int*)d_in[2];
    const int*   gid      = (const int*)d_in[3];
    const float* gamma    = (const float*)d_in[4];
    const float* beta     = (const float*)d_in[5];
    const float *W1[6], *b1[6], *W2[6], *b2[6];
    for (int i = 0; i < 6; ++i) {
        W1[i] = (const float*)d_in[6 + 4 * i];
        b1[i] = (const float*)d_in[7 + 4 * i];
        W2[i] = (const float*)d_in[8 + 4 * i];
        b2[i] = (const float*)d_in[9 + 4 * i];
    }
    const float* centroids = (const float*)d_in[30];
    const float* fc_w      = (const float*)d_in[31];
    const float* fc_b      = (const float*)d_in[32];

    const int N = N_NODES, E = N_EDGES;

    char* p = (char*)d_ws;
    size_t off = 0;
    auto alloc = [&](size_t bytes) {
        void* r = p + off;
        off += (bytes + 255) & ~(size_t)255;
        return r;
    };

    float* X0bn = (float*)alloc((size_t)N * IN_FEAT * 4);
    char* xz0 = p + off;
    float* XL[6];
    const int LCC[6] = {32, 32, 64, 64, 128, 128};
    for (int i = 0; i < 6; ++i) XL[i] = (float*)alloc((size_t)N * LCC[i] * 4);
    size_t xzbytes = (size_t)((p + off) - xz0);

    u16* Ubf = (u16*)alloc((size_t)N * 128 * 2);
    u16* Vbf = (u16*)alloc((size_t)N * 128 * 2);
    float* distb = (float*)Ubf;  // overlay: U/V dead once dist runs

    int*   row_off = (int*)alloc((size_t)(N + 1) * 4);
    int*   csr_src = (int*)alloc((size_t)E * 4);
    int*   csr_dst = (int*)alloc((size_t)E * 4);
    float* deg_inv = (float*)alloc((size_t)N * 4);
    u16*   w1img   = (u16*)alloc((size_t)W1TOT * 2);
    u16*   w2img   = (u16*)alloc((size_t)W2TOT * 2);
    u16*   centimg = (u16*)alloc((size_t)CTOT * 2);
    float* csq     = (float*)alloc(112 * 4);

    char*  zero0   = (char*)(p + off);
    int*   counts  = (int*)alloc((size_t)N * 4);
    int*   cursor  = (int*)alloc((size_t)N * 4);
    float* bnacc   = (float*)alloc(64);
    size_t zbytes  = (size_t)((char*)(p + off) - zero0);

    hipMemsetAsync(xz0, 0, xzbytes, stream);
    hipMemsetAsync(zero0, 0, zbytes, stream);

    bn_stats_kernel<<<(N + 255) / 256, 256, 0, stream>>>(features, bnacc, N);
    hist_kernel<<<(E + 255) / 256, 256, 0, stream>>>(dst, counts, E);
    scan_kernel<<<1, 1024, 0, stream>>>(counts, row_off, deg_inv, N);
    csr_fill_kernel<<<(E + 255) / 256, 256, 0, stream>>>(dst, src, row_off, cursor, csr_src, csr_dst, E);
    bn_norm_kernel<<<(N * IN_FEAT + 255) / 256, 256, 0, stream>>>(features, bnacc, gamma, beta, X0bn, N);

    PrepArgs pa;
    for (int i = 0; i < 6; ++i) { pa.w1[i] = W1[i]; pa.w2[i] = W2[i]; }
    pa.cent = centroids; pa.w1img = w1img; pa.w2img = w2img;
    pa.centimg = centimg; pa.csq = csq;
    megaprep_kernel<<<(PREP_TOT + 255) / 256, 256, 0, stream>>>(pa);

    const int NB = (N + 31) / 32;
    const int EB = (E + 63) / 64;

    node_mfma_kernel<5, 32, 32><<<NB, 256, 0, stream>>>(
        X0bn, (const float*)nullptr, w1img + W1OFF_H[0], b1[0], Ubf, Vbf, N);
    edge_agg_kernel<32><<<EB, 256, 0, stream>>>(
        Ubf, Vbf, csr_src, csr_dst, w2img + W2OFF_H[0], b2[0], XL[0], E);

    node_mfma_kernel<32, 32, 32><<<NB, 256, 0, stream>>>(
        XL[0], deg_inv, w1img + W1OFF_H[1], b1[1], Ubf, Vbf, N);
    edge_agg_kernel<32><<<EB, 256, 0, stream>>>(
        Ubf, Vbf, csr_src, csr_dst, w2img + W2OFF_H[1], b2[1], XL[1], E);

    node_mfma_kernel<32, 32, 64><<<NB, 256, 0, stream>>>(
        XL[1], deg_inv, w1img + W1OFF_H[2], b1[2], Ubf, Vbf, N);
    edge_agg_kernel<64><<<EB, 256, 0, stream>>>(
        Ubf, Vbf, csr_src, csr_dst, w2img + W2OFF_H[2], b2[2], XL[2], E);

    node_mfma_kernel<64, 64, 64><<<NB, 256, 0, stream>>>(
        XL[2], deg_inv, w1img + W1OFF_H[3], b1[3], Ubf, Vbf, N);
    edge_agg_kernel<64><<<EB, 256, 0, stream>>>(
        Ubf, Vbf, csr_src, csr_dst, w2img + W2OFF_H[3], b2[3], XL[3], E);

    node_mfma_kernel<64, 64, 128><<<NB, 256, 0, stream>>>(
        XL[3], deg_inv, w1img + W1OFF_H[4], b1[4], Ubf, Vbf, N);
    edge_agg_kernel<128><<<EB, 256, 0, stream>>>(
        Ubf, Vbf, csr_src, csr_dst, w2img + W2OFF_H[4], b2[4], XL[4], E);

    node_mfma_kernel<128, 128, 128><<<NB, 256, 0, stream>>>(
        XL[4], deg_inv, w1img + W1OFF_H[5], b1[5], Ubf, Vbf, N);
    edge_agg_kernel<128><<<EB, 256, 0, stream>>>(
        Ubf, Vbf, csr_src, csr_dst, w2img + W2OFF_H[5], b2[5], XL[5], E);

    dist_mfma_kernel<<<(N + 63) / 64, 256, 0, stream>>>(XL[5], deg_inv, centimg, csq, distb, N);
    pool_fc_kernel<<<N_GRAPHS, 128, 0, stream>>>(distb, gid, fc_w, fc_b, (float*)d_out, N);
}

// Round 6
// 633.627 us; speedup vs baseline: 4.4986x; 1.0583x over previous
//
#include <hip/hip_runtime.h>
#include <hip/hip_fp16.h>

// ---------------------------------------------------------------------------
// HyperbolicGNN: BN -> 6x EdgeConv -> centroid dist -> pool -> FC
// fp16 datapath (v_pk_add/max_f16 staging), f16 MFMA 16x16x32, fp32 accum.
// EdgeConv: U=X@(W1a-W1b)+b1, V=X@W1b (node MFMA GEMM);
//   edge_agg: h1=relu(U[dst]+V[src]) -> MFMA @W2 -> relu -> LDS tile ->
//   segmented scan over CSR dst -> fp32 atomicAdd into Xout (unscaled).
// deg_inv deferred into the NEXT consumer's A-staging.
// ---------------------------------------------------------------------------
#define N_NODES 30000
#define N_EDGES 480000
#define N_GRAPHS 128
#define IN_FEAT 5
#define NUM_CENTROID 100
#define BN_EPS 1e-5f

typedef unsigned int u32;
typedef unsigned short u16;

using half8 = __attribute__((ext_vector_type(8))) _Float16;
using h2    = __attribute__((ext_vector_type(2))) _Float16;
using f32x4 = __attribute__((ext_vector_type(4))) float;

__device__ __forceinline__ u16 f2h(float x) {
    return __half_as_ushort(__float2half_rn(x));
}
__device__ __forceinline__ float h2f(u16 h) {
    return __half2float(__ushort_as_half(h));
}
__device__ __forceinline__ u32 pack2h(float lo, float hi) {
    return (u32)f2h(lo) | ((u32)f2h(hi) << 16);
}

// ---------------------------------------------------------------------------
// setup1: bn_stats (blocks [0,118)) + dst histogram (blocks [118, 118+1875))
// ---------------------------------------------------------------------------
#define BN_BLKS 118
__global__ __launch_bounds__(256) void setup1_kernel(
    const float* __restrict__ f, float* __restrict__ acc,
    const int* __restrict__ dst, int* __restrict__ counts)
{
    __shared__ float s[10];
    const int b = blockIdx.x;
    if (b < BN_BLKS) {
        if (threadIdx.x < 10) s[threadIdx.x] = 0.f;
        __syncthreads();
        int n = b * 256 + threadIdx.x;
        if (n < N_NODES) {
            #pragma unroll
            for (int k = 0; k < IN_FEAT; ++k) {
                float v = f[n * IN_FEAT + k];
                atomicAdd(&s[k], v);
                atomicAdd(&s[5 + k], v * v);
            }
        }
        __syncthreads();
        if (threadIdx.x < 10) atomicAdd(&acc[threadIdx.x], s[threadIdx.x]);
    } else {
        int e = (b - BN_BLKS) * 256 + threadIdx.x;
        if (e < N_EDGES) atomicAdd(&counts[dst[e]], 1);
    }
}

// ---------------------------------------------------------------------------
// scan: row offsets + deg_inv (single block)
// ---------------------------------------------------------------------------
__global__ __launch_bounds__(1024) void scan_kernel(
    const int* __restrict__ counts, int* __restrict__ row_off,
    float* __restrict__ deg_inv, int N)
{
    __shared__ int s[1024];
    const int CH = 30;
    int t = threadIdx.x;
    int base = t * CH;
    int loc = 0;
    for (int j = 0; j < CH; ++j) {
        int i = base + j;
        if (i < N) loc += counts[i];
    }
    s[t] = loc;
    __syncthreads();
    for (int off = 1; off < 1024; off <<= 1) {
        int v = (t >= off) ? s[t - off] : 0;
        __syncthreads();
        s[t] += v;
        __syncthreads();
    }
    int run = s[t] - loc;
    for (int j = 0; j < CH; ++j) {
        int i = base + j;
        if (i < N) {
            int cv = counts[i];
            row_off[i] = run;
            run += cv;
            deg_inv[i] = 1.0f / fmaxf((float)cv, 1.0f);
        }
    }
    if (t == 1023) row_off[N] = s[1023];
}

// ---------------------------------------------------------------------------
// setup2: csr_fill + bn_norm + megaprep (all weight/centroid fp16 images,
// [n_out][k] k-major with XOR-16B swizzle) in one launch.
// ---------------------------------------------------------------------------
__constant__ __device__ const int LFIN[6] = {5, 32, 32, 64, 64, 128};
__constant__ __device__ const int LKD[6]  = {32, 32, 32, 64, 64, 128};
__constant__ __device__ const int LCD[6]  = {32, 32, 64, 64, 128, 128};
__constant__ __device__ const int W1OFF[6] = {0, 2048, 4096, 8192, 16384, 32768};
__constant__ __device__ const int W2OFF[6] = {0, 1024, 2048, 6144, 10240, 26624};
#define W1TOT 65536
#define W2TOT 43008
#define CTOT  14336  // 112*128
#define PREP_TOT (W1TOT + W2TOT + CTOT + 112)

#define CSR_BLKS 1875
#define BNN_BLKS 586

struct Setup2Args {
    const int* dst; const int* src; const int* row_off; int* cursor;
    int* csr_src; int* csr_dst;
    const float* f; const float* acc; const float* gamma; const float* beta;
    float* X0;
    const float* w1[6]; const float* w2[6]; const float* cent;
    u16* w1img; u16* w2img; u16* centimg; float* csq;
};

__global__ __launch_bounds__(256) void setup2_kernel(Setup2Args a)
{
    const int b = blockIdx.x;
    if (b < CSR_BLKS) {
        int e = b * 256 + threadIdx.x;
        if (e < N_EDGES) {
            int d = a.dst[e];
            int p = atomicAdd(&a.cursor[d], 1);
            a.csr_src[a.row_off[d] + p] = a.src[e];
            a.csr_dst[a.row_off[d] + p] = d;
        }
        return;
    }
    if (b < CSR_BLKS + BNN_BLKS) {
        int i = (b - CSR_BLKS) * 256 + threadIdx.x;
        if (i < N_NODES * IN_FEAT) {
            int k = i % IN_FEAT;
            float mu = a.acc[k] / (float)N_NODES;
            float var = a.acc[5 + k] / (float)N_NODES - mu * mu;
            float sc = a.gamma[k] / sqrtf(var + BN_EPS);
            a.X0[i] = (a.f[i] - mu) * sc + a.beta[k];
        }
        return;
    }
    int gid = (b - CSR_BLKS - BNN_BLKS) * 256 + threadIdx.x;
    if (gid < W1TOT) {
        int l = 0;
        #pragma unroll
        for (int i = 1; i < 6; ++i) if (gid >= W1OFF[i]) l = i;
        int local = gid - W1OFF[l];
        int K = LKD[l], C = LCD[l], F = LFIN[l];
        int n = local / K, k = local % K;
        float v = 0.f;
        if (k < F) {
            if (n < C) v = a.w1[l][k * C + n] - a.w1[l][(F + k) * C + n];
            else       v = a.w1[l][(F + k) * C + (n - C)];
        }
        int byte = (local * 2) ^ ((n & 7) << 4);
        *(u16*)((char*)a.w1img + (size_t)W1OFF[l] * 2 + byte) = f2h(v);
        return;
    }
    int g2 = gid - W1TOT;
    if (g2 < W2TOT) {
        int l = 0;
        #pragma unroll
        for (int i = 1; i < 6; ++i) if (g2 >= W2OFF[i]) l = i;
        int local = g2 - W2OFF[l];
        int C = LCD[l];
        int n = local / C, k = local % C;
        float v = a.w2[l][k * C + n];
        int byte = (local * 2) ^ ((n & 7) << 4);
        *(u16*)((char*)a.w2img + (size_t)W2OFF[l] * 2 + byte) = f2h(v);
        return;
    }
    int g3 = g2 - W2TOT;
    if (g3 < CTOT) {
        int c = g3 / 128, d = g3 % 128;
        float v = (c < NUM_CENTROID) ? a.cent[c * 128 + d] : 0.f;
        int byte = (g3 * 2) ^ ((c & 7) << 4);
        *(u16*)((char*)a.centimg + byte) = f2h(v);
        return;
    }
    int c = g3 - CTOT;
    if (c < 112) {
        float s = 0.f;
        if (c < NUM_CENTROID) {
            for (int d = 0; d < 128; ++d) {
                float cv = h2f(f2h(a.cent[c * 128 + d]));
                s += cv * cv;
            }
        }
        a.csq[c] = s;
    }
}

// ---------------------------------------------------------------------------
// Node MFMA GEMM: [32 nodes] x [2C cols], fp16 in/out, fp32 accum.
//   cols < C  -> U = (x*scale) @ (W1a-W1b) + b1 ;  cols >= C -> V = (x*scale) @ W1b
// ---------------------------------------------------------------------------
template <int FIN, int K, int C>
__global__ __launch_bounds__(256) void node_mfma_kernel(
    const float* __restrict__ Xin, const float* __restrict__ scale,
    const u16* __restrict__ w1img, const float* __restrict__ b1,
    u16* __restrict__ U, u16* __restrict__ V, int N)
{
    constexpr int COLS = 2 * C;
    __shared__ u16 wt[COLS * K];
    __shared__ u16 xt[32 * K];

    for (int i = threadIdx.x; i < COLS * K / 8; i += 256)
        reinterpret_cast<uint4*>(wt)[i] = reinterpret_cast<const uint4*>(w1img)[i];

    constexpr int DPT = K / 8;
    const int nl = threadIdx.x >> 3;
    const int part = threadIdx.x & 7;
    const int n = blockIdx.x * 32 + nl;
    const int k0 = part * DPT;
    const bool vld = (n < N);
    float s = 1.f;
    if (vld && scale) s = scale[n];

    float xv[DPT];
    if constexpr (FIN == K) {
        #pragma unroll
        for (int j4 = 0; j4 < DPT / 4; ++j4) {
            float4 f4 = {0, 0, 0, 0};
            if (vld) f4 = *reinterpret_cast<const float4*>(Xin + (size_t)n * FIN + k0 + j4 * 4);
            xv[j4 * 4 + 0] = f4.x * s; xv[j4 * 4 + 1] = f4.y * s;
            xv[j4 * 4 + 2] = f4.z * s; xv[j4 * 4 + 3] = f4.w * s;
        }
    } else {
        #pragma unroll
        for (int j = 0; j < DPT; ++j) {
            int k = k0 + j;
            xv[j] = (vld && k < FIN) ? Xin[(size_t)n * FIN + k] * s : 0.f;
        }
    }

    if constexpr (DPT == 4) {
        u32 o[2];
        o[0] = pack2h(xv[0], xv[1]);
        o[1] = pack2h(xv[2], xv[3]);
        int byte = ((nl * K + k0) * 2) ^ ((nl & 7) << 4);
        *reinterpret_cast<uint2*>((char*)xt + byte) = *reinterpret_cast<uint2*>(o);
    } else {
        #pragma unroll
        for (int j8 = 0; j8 < DPT / 8; ++j8) {
            u32 o[4];
            #pragma unroll
            for (int q = 0; q < 4; ++q)
                o[q] = pack2h(xv[j8 * 8 + q * 2], xv[j8 * 8 + q * 2 + 1]);
            int byte = ((nl * K + k0 + j8 * 8) * 2) ^ ((nl & 7) << 4);
            *reinterpret_cast<uint4*>((char*)xt + byte) = *reinterpret_cast<uint4*>(o);
        }
    }
    __syncthreads();

    constexpr int NT = COLS / 16;
    constexpr int NPW = NT / 4;   // 1, 2, 4
    constexpr int KS = K / 32;

    const int wid = threadIdx.x >> 6;
    const int lane = threadIdx.x & 63;
    const int lrow = lane & 15;
    const int lk8 = (lane >> 4) * 8;

    f32x4 acc[2][NPW] = {};

    #pragma unroll
    for (int ks = 0; ks < KS; ++ks) {
        half8 afrag[2];
        #pragma unroll
        for (int m = 0; m < 2; ++m) {
            int row = m * 16 + lrow;
            int byte = ((row * K + ks * 32 + lk8) * 2) ^ ((row & 7) << 4);
            afrag[m] = *reinterpret_cast<const half8*>((const char*)xt + byte);
        }
        #pragma unroll
        for (int nn = 0; nn < NPW; ++nn) {
            int colr = (wid * NPW + nn) * 16 + lrow;
            int byte = ((colr * K + ks * 32 + lk8) * 2) ^ ((colr & 7) << 4);
            half8 bfrag = *reinterpret_cast<const half8*>((const char*)wt + byte);
            #pragma unroll
            for (int m = 0; m < 2; ++m)
                acc[m][nn] = __builtin_amdgcn_mfma_f32_16x16x32_f16(
                    afrag[m], bfrag, acc[m][nn], 0, 0, 0);
        }
    }

    #pragma unroll
    for (int nn = 0; nn < NPW; ++nn) {
        int colr = (wid * NPW + nn) * 16 + lrow;
        float bias = (colr < C) ? b1[colr] : 0.f;
        #pragma unroll
        for (int m = 0; m < 2; ++m) {
            #pragma unroll
            for (int j = 0; j < 4; ++j) {
                int row = m * 16 + (lane >> 4) * 4 + j;
                int node = blockIdx.x * 32 + row;
                if (node < N) {
                    float z = acc[m][nn][j] + bias;
                    if (colr < C) U[(size_t)node * C + colr] = f2h(z);
                    else          V[(size_t)node * C + colr - C] = f2h(z);
                }
            }
        }
    }
}

// ---------------------------------------------------------------------------
// Fused edge GEMM + segmented reduction. ET edges per block.
// h1 staging via packed fp16 add/max (v_pk_add_f16 / v_pk_max_f16).
// ---------------------------------------------------------------------------
template <int C, int ET>
__global__ __launch_bounds__(256) void edge_agg_kernel(
    const u16* __restrict__ U, const u16* __restrict__ V,
    const int* __restrict__ csr_src, const int* __restrict__ csr_dst,
    const u16* __restrict__ w2img, const float* __restrict__ b2,
    float* __restrict__ Xout, int E)
{
    constexpr int PAD = 2;
    __shared__ u16 w2t[C * C];
    __shared__ u16 at[ET * (C + PAD)];  // A-tile (ET*C swizzled), then h2 [ET][C+PAD]
    __shared__ int dstid[ET];

    for (int i = threadIdx.x; i < C * C / 8; i += 256)
        reinterpret_cast<uint4*>(w2t)[i] = reinterpret_cast<const uint4*>(w2img)[i];

    constexpr int TPE = 256 / ET;   // threads per edge; 32 features per thread
    const int e_loc = threadIdx.x / TPE;
    const int part  = threadIdx.x % TPE;
    const int k0 = part * 32;
    const int e = blockIdx.x * ET + e_loc;
    const bool valid = (e < E);
    const int dn = valid ? csr_dst[e] : 0;
    const int sn = valid ? csr_src[e] : 0;
    if (part == 0) dstid[e_loc] = valid ? dn : -1;

    const h2 zz = {(_Float16)0.f, (_Float16)0.f};
    const u16* Ur = U + (size_t)dn * C + k0;
    const u16* Vr = V + (size_t)sn * C + k0;
    #pragma unroll
    for (int j = 0; j < 4; ++j) {
        uint4 uu = {0, 0, 0, 0}, vv = {0, 0, 0, 0};
        if (valid) {
            uu = *reinterpret_cast<const uint4*>(Ur + j * 8);
            vv = *reinterpret_cast<const uint4*>(Vr + j * 8);
        }
        h2 o[4];
        const h2* ua = reinterpret_cast<const h2*>(&uu);
        const h2* va = reinterpret_cast<const h2*>(&vv);
        #pragma unroll
        for (int q = 0; q < 4; ++q)
            o[q] = __builtin_elementwise_max(ua[q] + va[q], zz);
        int byte = ((e_loc * C + k0 + j * 8) * 2) ^ ((e_loc & 7) << 4);
        *reinterpret_cast<uint4*>((char*)at + byte) = *reinterpret_cast<const uint4*>(o);
    }
    __syncthreads();

    constexpr int MT = ET / 16;
    constexpr int NT = C / 16;
    constexpr int WN = (NT < 4) ? NT : 4;
    constexpr int WM = 4 / WN;
    constexpr int MPW = MT / WM;
    constexpr int NPW = NT / WN;
    constexpr int KS = C / 32;

    const int wid = threadIdx.x >> 6;
    const int lane = threadIdx.x & 63;
    const int wn = wid % WN;
    const int wm = wid / WN;
    const int lrow = lane & 15;
    const int lk8 = (lane >> 4) * 8;

    f32x4 acc[MPW][NPW] = {};

    #pragma unroll
    for (int ks = 0; ks < KS; ++ks) {
        half8 afrag[MPW], bfrag[NPW];
        #pragma unroll
        for (int m = 0; m < MPW; ++m) {
            int row = (wm * MPW + m) * 16 + lrow;
            int byte = ((row * C + ks * 32 + lk8) * 2) ^ ((row & 7) << 4);
            afrag[m] = *reinterpret_cast<const half8*>((const char*)at + byte);
        }
        #pragma unroll
        for (int n = 0; n < NPW; ++n) {
            int col = (wn * NPW + n) * 16 + lrow;
            int byte = ((col * C + ks * 32 + lk8) * 2) ^ ((col & 7) << 4);
            bfrag[n] = *reinterpret_cast<const half8*>((const char*)w2t + byte);
        }
        #pragma unroll
        for (int m = 0; m < MPW; ++m)
            #pragma unroll
            for (int n = 0; n < NPW; ++n)
                acc[m][n] = __builtin_amdgcn_mfma_f32_16x16x32_f16(
                    afrag[m], bfrag[n], acc[m][n], 0, 0, 0);
    }
    __syncthreads();

    #pragma unroll
    for (int m = 0; m < MPW; ++m) {
        #pragma unroll
        for (int n = 0; n < NPW; ++n) {
            int col = (wn * NPW + n) * 16 + lrow;
            float bb = b2[col];
            #pragma unroll
            for (int j = 0; j < 4; ++j) {
                int row = (wm * MPW + m) * 16 + (lane >> 4) * 4 + j;
                at[row * (C + PAD) + col] = f2h(fmaxf(acc[m][n][j] + bb, 0.f));
            }
        }
    }
    __syncthreads();

    // segmented scan: 256/C groups x C cols; 32 edges per thread
    constexpr int EPS = ET * C / 256;  // == 32
    const int col = threadIdx.x & (C - 1);
    const int e0 = (threadIdx.x / C) * EPS;
    float sum = 0.f;
    int cur = dstid[e0];
    #pragma unroll 4
    for (int ee = e0; ee < e0 + EPS; ++ee) {
        int d = dstid[ee];
        if (d != cur) {
            if (cur >= 0) atomicAdd(&Xout[(size_t)cur * C + col], sum);
            sum = 0.f;
            cur = d;
        }
        sum += h2f(at[ee * (C + PAD) + col]);
    }
    if (cur >= 0) atomicAdd(&Xout[(size_t)cur * C + col], sum);
}

// ---------------------------------------------------------------------------
// Centroid distances via MFMA: dist^2 = |x|^2 - 2 x.c + |c|^2 (fp16 operands)
// ---------------------------------------------------------------------------
__global__ __launch_bounds__(256) void dist_mfma_kernel(
    const float* __restrict__ X, const float* __restrict__ scale,
    const u16* __restrict__ centimg, const float* __restrict__ csq,
    float* __restrict__ dist, int N)
{
    __shared__ u16 ct[112 * 128];
    __shared__ u16 xt[64 * 128];
    __shared__ float xsqp[64][4];
    __shared__ float csqs[112];

    for (int i = threadIdx.x; i < 112 * 128 / 8; i += 256)
        reinterpret_cast<uint4*>(ct)[i] = reinterpret_cast<const uint4*>(centimg)[i];
    if (threadIdx.x < 112) csqs[threadIdx.x] = csq[threadIdx.x];

    const int nl = threadIdx.x >> 2;
    const int part = threadIdx.x & 3;
    const int n = blockIdx.x * 64 + nl;
    const int k0 = part * 32;
    const bool vld = (n < N);
    const float s = vld ? scale[n] : 0.f;

    float ss = 0.f;
    #pragma unroll
    for (int j8 = 0; j8 < 4; ++j8) {
        float4 f0 = {0, 0, 0, 0}, f1 = {0, 0, 0, 0};
        if (vld) {
            f0 = *reinterpret_cast<const float4*>(X + (size_t)n * 128 + k0 + j8 * 8);
            f1 = *reinterpret_cast<const float4*>(X + (size_t)n * 128 + k0 + j8 * 8 + 4);
        }
        float xv[8] = {f0.x * s, f0.y * s, f0.z * s, f0.w * s,
                       f1.x * s, f1.y * s, f1.z * s, f1.w * s};
        u32 o[4];
        #pragma unroll
        for (int q = 0; q < 4; ++q) {
            float lo = h2f(f2h(xv[q * 2]));
            float hi = h2f(f2h(xv[q * 2 + 1]));
            ss += lo * lo + hi * hi;
            o[q] = pack2h(xv[q * 2], xv[q * 2 + 1]);
        }
        int byte = ((nl * 128 + k0 + j8 * 8) * 2) ^ ((nl & 7) << 4);
        *reinterpret_cast<uint4*>((char*)xt + byte) = *reinterpret_cast<uint4*>(o);
    }
    xsqp[nl][part] = ss;
    __syncthreads();

    const int wid = threadIdx.x >> 6;
    const int lane = threadIdx.x & 63;
    const int lrow = lane & 15;
    const int lk8 = (lane >> 4) * 8;

    f32x4 acc[7] = {};
    #pragma unroll
    for (int ks = 0; ks < 4; ++ks) {
        int row = wid * 16 + lrow;
        int byte = ((row * 128 + ks * 32 + lk8) * 2) ^ ((row & 7) << 4);
        half8 afrag = *reinterpret_cast<const half8*>((const char*)xt + byte);
        #pragma unroll
        for (int nn = 0; nn < 7; ++nn) {
            int colr = nn * 16 + lrow;
            int bb = ((colr * 128 + ks * 32 + lk8) * 2) ^ ((colr & 7) << 4);
            half8 bfrag = *reinterpret_cast<const half8*>((const char*)ct + bb);
            acc[nn] = __builtin_amdgcn_mfma_f32_16x16x32_f16(afrag, bfrag, acc[nn], 0, 0, 0);
        }
    }

    float xs[4];
    #pragma unroll
    for (int j = 0; j < 4; ++j) {
        int row = wid * 16 + (lane >> 4) * 4 + j;
        xs[j] = xsqp[row][0] + xsqp[row][1] + xsqp[row][2] + xsqp[row][3];
    }
    #pragma unroll
    for (int nn = 0; nn < 7; ++nn) {
        int colr = nn * 16 + lrow;
        if (colr < NUM_CENTROID) {
            float cq = csqs[colr];
            #pragma unroll
            for (int j = 0; j < 4; ++j) {
                int row = wid * 16 + (lane >> 4) * 4 + j;
                int node = blockIdx.x * 64 + row;
                if (node < N) {
                    float v = xs[j] - 2.f * acc[nn][j] + cq;
                    dist[(size_t)node * NUM_CENTROID + colr] = sqrtf(fmaxf(v, 0.f) + 1e-12f);
                }
            }
        }
    }
}

// ---------------------------------------------------------------------------
// Per-graph pooling + FC
// ---------------------------------------------------------------------------
__global__ __launch_bounds__(128) void pool_fc_kernel(
    const float* __restrict__ dist, const int* __restrict__ gid,
    const float* __restrict__ fc_w, const float* __restrict__ fc_b,
    float* __restrict__ out, int N)
{
    __shared__ float pooled[NUM_CENTROID];
    const int g = blockIdx.x;
    const int t = threadIdx.x;

    int lo = 0, hi = N;
    while (lo < hi) { int mid = (lo + hi) >> 1; if (gid[mid] < g) lo = mid + 1; else hi = mid; }
    const int start = lo;
    hi = N;
    while (lo < hi) { int mid = (lo + hi) >> 1; if (gid[mid] < g + 1) lo = mid + 1; else hi = mid; }
    const int end = lo;

    if (t < NUM_CENTROID) {
        float s = 0.f;
        for (int n = start; n < end; ++n) s += dist[(size_t)n * NUM_CENTROID + t];
        pooled[t] = s / fmaxf((float)(end - start), 1.0f);
    }
    __syncthreads();
    if (t < 2) {
        float o = fc_b[t];
        for (int c = 0; c < NUM_CENTROID; ++c) o += pooled[c] * fc_w[c * 2 + t];
        out[g * 2 + t] = o;
    }
}

// ---------------------------------------------------------------------------
// Host launch
// ---------------------------------------------------------------------------
static const int W1OFF_H[6] = {0, 2048, 4096, 8192, 16384, 32768};
static const int W2OFF_H[6] = {0, 1024, 2048, 6144, 10240, 26624};

extern "C" void kernel_launch(void* const* d_in, const int* in_sizes, int n_in,
                              void* d_out, int out_size, void* d_ws, size_t ws_size,
                              hipStream_t stream) {
    const float* features = (const float*)d_in[0];
    const int*   src      = (const int*)d_in[1];
    const int*   dst      = (const int*)d_in[2];
    const int*   gid      = (const int*)d_in[3];
    const float* gamma    = (const float*)d_in[4];
    const float* beta     = (const float*)d_in[5];
    const float *W1[6], *b1[6], *W2[6], *b2[6];
    for (int i = 0; i < 6; ++i) {
        W1[i] = (const float*)d_in[6 + 4 * i];
        b1[i] = (const float*)d_in[7 + 4 * i];
        W2[i] = (const float*)d_in[8 + 4 * i];
        b2[i] = (const float*)d_in[9 + 4 * i];
    }
    const float* centroids = (const float*)d_in[30];
    const float* fc_w      = (const float*)d_in[31];
    const float* fc_b      = (const float*)d_in[32];

    const int N = N_NODES, E = N_EDGES;

    char* p = (char*)d_ws;
    size_t off = 0;
    auto alloc = [&](size_t bytes) {
        void* r = p + off;
        off += (bytes + 255) & ~(size_t)255;
        return r;
    };

    float* X0bn = (float*)alloc((size_t)N * IN_FEAT * 4);
    char* xz0 = p + off;
    float* XL[6];
    const int LCC[6] = {32, 32, 64, 64, 128, 128};
    for (int i = 0; i < 6; ++i) XL[i] = (float*)alloc((size_t)N * LCC[i] * 4);
    size_t xzbytes = (size_t)((p + off) - xz0);

    u16* Uh = (u16*)alloc((size_t)N * 128 * 2);
    u16* Vh = (u16*)alloc((size_t)N * 128 * 2);
    float* distb = (float*)Uh;  // overlay: U/V dead once dist runs

    int*   row_off = (int*)alloc((size_t)(N + 1) * 4);
    int*   csr_src = (int*)alloc((size_t)E * 4);
    int*   csr_dst = (int*)alloc((size_t)E * 4);
    float* deg_inv = (float*)alloc((size_t)N * 4);
    u16*   w1img   = (u16*)alloc((size_t)W1TOT * 2);
    u16*   w2img   = (u16*)alloc((size_t)W2TOT * 2);
    u16*   centimg = (u16*)alloc((size_t)CTOT * 2);
    float* csq     = (float*)alloc(112 * 4);

    char*  zero0   = (char*)(p + off);
    int*   counts  = (int*)alloc((size_t)N * 4);
    int*   cursor  = (int*)alloc((size_t)N * 4);
    float* bnacc   = (float*)alloc(64);
    size_t zbytes  = (size_t)((char*)(p + off) - zero0);

    (void)hipMemsetAsync(xz0, 0, xzbytes, stream);
    (void)hipMemsetAsync(zero0, 0, zbytes, stream);

    setup1_kernel<<<BN_BLKS + 1875, 256, 0, stream>>>(features, bnacc, dst, counts);
    scan_kernel<<<1, 1024, 0, stream>>>(counts, row_off, deg_inv, N);

    Setup2Args sa;
    sa.dst = dst; sa.src = src; sa.row_off = row_off; sa.cursor = cursor;
    sa.csr_src = csr_src; sa.csr_dst = csr_dst;
    sa.f = features; sa.acc = bnacc; sa.gamma = gamma; sa.beta = beta; sa.X0 = X0bn;
    for (int i = 0; i < 6; ++i) { sa.w1[i] = W1[i]; sa.w2[i] = W2[i]; }
    sa.cent = centroids; sa.w1img = w1img; sa.w2img = w2img;
    sa.centimg = centimg; sa.csq = csq;
    const int S2B = CSR_BLKS + BNN_BLKS + (PREP_TOT + 255) / 256;
    setup2_kernel<<<S2B, 256, 0, stream>>>(sa);

    const int NB = (N + 31) / 32;

    node_mfma_kernel<5, 32, 32><<<NB, 256, 0, stream>>>(
        X0bn, (const float*)nullptr, w1img + W1OFF_H[0], b1[0], Uh, Vh, N);
    edge_agg_kernel<32, 256><<<(E + 255) / 256, 256, 0, stream>>>(
        Uh, Vh, csr_src, csr_dst, w2img + W2OFF_H[0], b2[0], XL[0], E);

    node_mfma_kernel<32, 32, 32><<<NB, 256, 0, stream>>>(
        XL[0], deg_inv, w1img + W1OFF_H[1], b1[1], Uh, Vh, N);
    edge_agg_kernel<32, 256><<<(E + 255) / 256, 256, 0, stream>>>(
        Uh, Vh, csr_src, csr_dst, w2img + W2OFF_H[1], b2[1], XL[1], E);

    node_mfma_kernel<32, 32, 64><<<NB, 256, 0, stream>>>(
        XL[1], deg_inv, w1img + W1OFF_H[2], b1[2], Uh, Vh, N);
    edge_agg_kernel<64, 128><<<(E + 127) / 128, 256, 0, stream>>>(
        Uh, Vh, csr_src, csr_dst, w2img + W2OFF_H[2], b2[2], XL[2], E);

    node_mfma_kernel<64, 64, 64><<<NB, 256, 0, stream>>>(
        XL[2], deg_inv, w1img + W1OFF_H[3], b1[3], Uh, Vh, N);
    edge_agg_kernel<64, 128><<<(E + 127) / 128, 256, 0, stream>>>(
        Uh, Vh, csr_src, csr_dst, w2img + W2OFF_H[3], b2[3], XL[3], E);

    node_mfma_kernel<64, 64, 128><<<NB, 256, 0, stream>>>(
        XL[3], deg_inv, w1img + W1OFF_H[4], b1[4], Uh, Vh, N);
    edge_agg_kernel<128, 64><<<(E + 63) / 64, 256, 0, stream>>>(
        Uh, Vh, csr_src, csr_dst, w2img + W2OFF_H[4], b2[4], XL[4], E);

    node_mfma_kernel<128, 128, 128><<<NB, 256, 0, stream>>>(
        XL[4], deg_inv, w1img + W1OFF_H[5], b1[5], Uh, Vh, N);
    edge_agg_kernel<128, 64><<<(E + 63) / 64, 256, 0, stream>>>(
        Uh, Vh, csr_src, csr_dst, w2img + W2OFF_H[5], b2[5], XL[5], E);

    dist_mfma_kernel<<<(N + 63) / 64, 256, 0, stream>>>(XL[5], deg_inv, centimg, csq, distb, N);
    pool_fc_kernel<<<N_GRAPHS, 128, 0, stream>>>(distb, gid, fc_w, fc_b, (float*)d_out, N);
}

// Round 7
// 572.769 us; speedup vs baseline: 4.9766x; 1.1063x over previous
//
#include <hip/hip_runtime.h>
#include <hip/hip_fp16.h>

// ---------------------------------------------------------------------------
// HyperbolicGNN: BN -> 6x EdgeConv -> centroid dist -> pool -> FC
// fp16 datapath, f16 MFMA 16x16x32, fp32 accum.
// edge_agg: W2 fragments held in REGISTERS (loaded from swizzled global
// image, L2-hot) -> LDS per block is just the h1/h2 tile (~17.6KB) -> 4
// blocks/CU instead of 3 (was w2t-LDS-capped at 49.6KB).
// ---------------------------------------------------------------------------
#define N_NODES 30000
#define N_EDGES 480000
#define N_GRAPHS 128
#define IN_FEAT 5
#define NUM_CENTROID 100
#define BN_EPS 1e-5f

typedef unsigned int u32;
typedef unsigned short u16;

using half8 = __attribute__((ext_vector_type(8))) _Float16;
using h2    = __attribute__((ext_vector_type(2))) _Float16;
using f32x4 = __attribute__((ext_vector_type(4))) float;

__device__ __forceinline__ u16 f2h(float x) {
    return __half_as_ushort(__float2half_rn(x));
}
__device__ __forceinline__ float h2f(u16 h) {
    return __half2float(__ushort_as_half(h));
}
__device__ __forceinline__ u32 pack2h(float lo, float hi) {
    return (u32)f2h(lo) | ((u32)f2h(hi) << 16);
}

// ---------------------------------------------------------------------------
// setup1: bn_stats (blocks [0,118)) + dst histogram (blocks [118, 118+1875))
// ---------------------------------------------------------------------------
#define BN_BLKS 118
__global__ __launch_bounds__(256) void setup1_kernel(
    const float* __restrict__ f, float* __restrict__ acc,
    const int* __restrict__ dst, int* __restrict__ counts)
{
    __shared__ float s[10];
    const int b = blockIdx.x;
    if (b < BN_BLKS) {
        if (threadIdx.x < 10) s[threadIdx.x] = 0.f;
        __syncthreads();
        int n = b * 256 + threadIdx.x;
        if (n < N_NODES) {
            #pragma unroll
            for (int k = 0; k < IN_FEAT; ++k) {
                float v = f[n * IN_FEAT + k];
                atomicAdd(&s[k], v);
                atomicAdd(&s[5 + k], v * v);
            }
        }
        __syncthreads();
        if (threadIdx.x < 10) atomicAdd(&acc[threadIdx.x], s[threadIdx.x]);
    } else {
        int e = (b - BN_BLKS) * 256 + threadIdx.x;
        if (e < N_EDGES) atomicAdd(&counts[dst[e]], 1);
    }
}

// ---------------------------------------------------------------------------
// scan: row offsets + deg_inv (single block)
// ---------------------------------------------------------------------------
__global__ __launch_bounds__(1024) void scan_kernel(
    const int* __restrict__ counts, int* __restrict__ row_off,
    float* __restrict__ deg_inv, int N)
{
    __shared__ int s[1024];
    const int CH = 30;
    int t = threadIdx.x;
    int base = t * CH;
    int loc = 0;
    for (int j = 0; j < CH; ++j) {
        int i = base + j;
        if (i < N) loc += counts[i];
    }
    s[t] = loc;
    __syncthreads();
    for (int off = 1; off < 1024; off <<= 1) {
        int v = (t >= off) ? s[t - off] : 0;
        __syncthreads();
        s[t] += v;
        __syncthreads();
    }
    int run = s[t] - loc;
    for (int j = 0; j < CH; ++j) {
        int i = base + j;
        if (i < N) {
            int cv = counts[i];
            row_off[i] = run;
            run += cv;
            deg_inv[i] = 1.0f / fmaxf((float)cv, 1.0f);
        }
    }
    if (t == 1023) row_off[N] = s[1023];
}

// ---------------------------------------------------------------------------
// setup2: csr_fill + bn_norm + megaprep (all weight/centroid fp16 images,
// [n_out][k] k-major with XOR-16B swizzle) in one launch.
// ---------------------------------------------------------------------------
__constant__ __device__ const int LFIN[6] = {5, 32, 32, 64, 64, 128};
__constant__ __device__ const int LKD[6]  = {32, 32, 32, 64, 64, 128};
__constant__ __device__ const int LCD[6]  = {32, 32, 64, 64, 128, 128};
__constant__ __device__ const int W1OFF[6] = {0, 2048, 4096, 8192, 16384, 32768};
__constant__ __device__ const int W2OFF[6] = {0, 1024, 2048, 6144, 10240, 26624};
#define W1TOT 65536
#define W2TOT 43008
#define CTOT  14336  // 112*128
#define PREP_TOT (W1TOT + W2TOT + CTOT + 112)

#define CSR_BLKS 1875
#define BNN_BLKS 586

struct Setup2Args {
    const int* dst; const int* src; const int* row_off; int* cursor;
    int* csr_src; int* csr_dst;
    const float* f; const float* acc; const float* gamma; const float* beta;
    float* X0;
    const float* w1[6]; const float* w2[6]; const float* cent;
    u16* w1img; u16* w2img; u16* centimg; float* csq;
};

__global__ __launch_bounds__(256) void setup2_kernel(Setup2Args a)
{
    const int b = blockIdx.x;
    if (b < CSR_BLKS) {
        int e = b * 256 + threadIdx.x;
        if (e < N_EDGES) {
            int d = a.dst[e];
            int p = atomicAdd(&a.cursor[d], 1);
            a.csr_src[a.row_off[d] + p] = a.src[e];
            a.csr_dst[a.row_off[d] + p] = d;
        }
        return;
    }
    if (b < CSR_BLKS + BNN_BLKS) {
        int i = (b - CSR_BLKS) * 256 + threadIdx.x;
        if (i < N_NODES * IN_FEAT) {
            int k = i % IN_FEAT;
            float mu = a.acc[k] / (float)N_NODES;
            float var = a.acc[5 + k] / (float)N_NODES - mu * mu;
            float sc = a.gamma[k] / sqrtf(var + BN_EPS);
            a.X0[i] = (a.f[i] - mu) * sc + a.beta[k];
        }
        return;
    }
    int gid = (b - CSR_BLKS - BNN_BLKS) * 256 + threadIdx.x;
    if (gid < W1TOT) {
        int l = 0;
        #pragma unroll
        for (int i = 1; i < 6; ++i) if (gid >= W1OFF[i]) l = i;
        int local = gid - W1OFF[l];
        int K = LKD[l], C = LCD[l], F = LFIN[l];
        int n = local / K, k = local % K;
        float v = 0.f;
        if (k < F) {
            if (n < C) v = a.w1[l][k * C + n] - a.w1[l][(F + k) * C + n];
            else       v = a.w1[l][(F + k) * C + (n - C)];
        }
        int byte = (local * 2) ^ ((n & 7) << 4);
        *(u16*)((char*)a.w1img + (size_t)W1OFF[l] * 2 + byte) = f2h(v);
        return;
    }
    int g2 = gid - W1TOT;
    if (g2 < W2TOT) {
        int l = 0;
        #pragma unroll
        for (int i = 1; i < 6; ++i) if (g2 >= W2OFF[i]) l = i;
        int local = g2 - W2OFF[l];
        int C = LCD[l];
        int n = local / C, k = local % C;
        float v = a.w2[l][k * C + n];
        int byte = (local * 2) ^ ((n & 7) << 4);
        *(u16*)((char*)a.w2img + (size_t)W2OFF[l] * 2 + byte) = f2h(v);
        return;
    }
    int g3 = g2 - W2TOT;
    if (g3 < CTOT) {
        int c = g3 / 128, d = g3 % 128;
        float v = (c < NUM_CENTROID) ? a.cent[c * 128 + d] : 0.f;
        int byte = (g3 * 2) ^ ((c & 7) << 4);
        *(u16*)((char*)a.centimg + byte) = f2h(v);
        return;
    }
    int c = g3 - CTOT;
    if (c < 112) {
        float s = 0.f;
        if (c < NUM_CENTROID) {
            for (int d = 0; d < 128; ++d) {
                float cv = h2f(f2h(a.cent[c * 128 + d]));
                s += cv * cv;
            }
        }
        a.csq[c] = s;
    }
}

// ---------------------------------------------------------------------------
// Node MFMA GEMM: [32 nodes] x [2C cols], fp16 in/out, fp32 accum.
//   cols < C  -> U = (x*scale) @ (W1a-W1b) + b1 ;  cols >= C -> V = (x*scale) @ W1b
// ---------------------------------------------------------------------------
template <int FIN, int K, int C>
__global__ __launch_bounds__(256) void node_mfma_kernel(
    const float* __restrict__ Xin, const float* __restrict__ scale,
    const u16* __restrict__ w1img, const float* __restrict__ b1,
    u16* __restrict__ U, u16* __restrict__ V, int N)
{
    constexpr int COLS = 2 * C;
    __shared__ u16 wt[COLS * K];
    __shared__ u16 xt[32 * K];

    for (int i = threadIdx.x; i < COLS * K / 8; i += 256)
        reinterpret_cast<uint4*>(wt)[i] = reinterpret_cast<const uint4*>(w1img)[i];

    constexpr int DPT = K / 8;
    const int nl = threadIdx.x >> 3;
    const int part = threadIdx.x & 7;
    const int n = blockIdx.x * 32 + nl;
    const int k0 = part * DPT;
    const bool vld = (n < N);
    float s = 1.f;
    if (vld && scale) s = scale[n];

    float xv[DPT];
    if constexpr (FIN == K) {
        #pragma unroll
        for (int j4 = 0; j4 < DPT / 4; ++j4) {
            float4 f4 = {0, 0, 0, 0};
            if (vld) f4 = *reinterpret_cast<const float4*>(Xin + (size_t)n * FIN + k0 + j4 * 4);
            xv[j4 * 4 + 0] = f4.x * s; xv[j4 * 4 + 1] = f4.y * s;
            xv[j4 * 4 + 2] = f4.z * s; xv[j4 * 4 + 3] = f4.w * s;
        }
    } else {
        #pragma unroll
        for (int j = 0; j < DPT; ++j) {
            int k = k0 + j;
            xv[j] = (vld && k < FIN) ? Xin[(size_t)n * FIN + k] * s : 0.f;
        }
    }

    if constexpr (DPT == 4) {
        u32 o[2];
        o[0] = pack2h(xv[0], xv[1]);
        o[1] = pack2h(xv[2], xv[3]);
        int byte = ((nl * K + k0) * 2) ^ ((nl & 7) << 4);
        *reinterpret_cast<uint2*>((char*)xt + byte) = *reinterpret_cast<uint2*>(o);
    } else {
        #pragma unroll
        for (int j8 = 0; j8 < DPT / 8; ++j8) {
            u32 o[4];
            #pragma unroll
            for (int q = 0; q < 4; ++q)
                o[q] = pack2h(xv[j8 * 8 + q * 2], xv[j8 * 8 + q * 2 + 1]);
            int byte = ((nl * K + k0 + j8 * 8) * 2) ^ ((nl & 7) << 4);
            *reinterpret_cast<uint4*>((char*)xt + byte) = *reinterpret_cast<uint4*>(o);
        }
    }
    __syncthreads();

    constexpr int NT = COLS / 16;
    constexpr int NPW = NT / 4;   // 1, 2, 4
    constexpr int KS = K / 32;

    const int wid = threadIdx.x >> 6;
    const int lane = threadIdx.x & 63;
    const int lrow = lane & 15;
    const int lk8 = (lane >> 4) * 8;

    f32x4 acc[2][NPW] = {};

    #pragma unroll
    for (int ks = 0; ks < KS; ++ks) {
        half8 afrag[2];
        #pragma unroll
        for (int m = 0; m < 2; ++m) {
            int row = m * 16 + lrow;
            int byte = ((row * K + ks * 32 + lk8) * 2) ^ ((row & 7) << 4);
            afrag[m] = *reinterpret_cast<const half8*>((const char*)xt + byte);
        }
        #pragma unroll
        for (int nn = 0; nn < NPW; ++nn) {
            int colr = (wid * NPW + nn) * 16 + lrow;
            int byte = ((colr * K + ks * 32 + lk8) * 2) ^ ((colr & 7) << 4);
            half8 bfrag = *reinterpret_cast<const half8*>((const char*)wt + byte);
            #pragma unroll
            for (int m = 0; m < 2; ++m)
                acc[m][nn] = __builtin_amdgcn_mfma_f32_16x16x32_f16(
                    afrag[m], bfrag, acc[m][nn], 0, 0, 0);
        }
    }

    #pragma unroll
    for (int nn = 0; nn < NPW; ++nn) {
        int colr = (wid * NPW + nn) * 16 + lrow;
        float bias = (colr < C) ? b1[colr] : 0.f;
        #pragma unroll
        for (int m = 0; m < 2; ++m) {
            #pragma unroll
            for (int j = 0; j < 4; ++j) {
                int row = m * 16 + (lane >> 4) * 4 + j;
                int node = blockIdx.x * 32 + row;
                if (node < N) {
                    float z = acc[m][nn][j] + bias;
                    if (colr < C) U[(size_t)node * C + colr] = f2h(z);
                    else          V[(size_t)node * C + colr - C] = f2h(z);
                }
            }
        }
    }
}

// ---------------------------------------------------------------------------
// Fused edge GEMM + segmented reduction. ET edges per block.
// W2 B-fragments in REGISTERS (global swizzled image, L2-hot) — LDS is only
// the h1/h2 tile -> ~17.6KB/block -> 4 blocks/CU (launch_bounds 256,4).
// ---------------------------------------------------------------------------
template <int C, int ET>
__global__ __launch_bounds__(256, 4) void edge_agg_kernel(
    const u16* __restrict__ U, const u16* __restrict__ V,
    const int* __restrict__ csr_src, const int* __restrict__ csr_dst,
    const u16* __restrict__ w2img, const float* __restrict__ b2,
    float* __restrict__ Xout, int E)
{
    constexpr int PAD = 2;
    __shared__ u16 at[ET * (C + PAD)];  // A-tile (ET*C swizzled), then h2 [ET][C+PAD]
    __shared__ int dstid[ET];

    constexpr int MT = ET / 16;
    constexpr int NT = C / 16;
    constexpr int WN = (NT < 4) ? NT : 4;
    constexpr int WM = 4 / WN;
    constexpr int MPW = MT / WM;
    constexpr int NPW = NT / WN;
    constexpr int KS = C / 32;

    const int wid = threadIdx.x >> 6;
    const int lane = threadIdx.x & 63;
    const int wn = wid % WN;
    const int wm = wid / WN;
    const int lrow = lane & 15;
    const int lk8 = (lane >> 4) * 8;

    // B-fragments from global swizzled image (uniform across blocks, L2-hot)
    half8 bfrag[NPW][KS];
    #pragma unroll
    for (int n = 0; n < NPW; ++n) {
        int col = (wn * NPW + n) * 16 + lrow;
        #pragma unroll
        for (int ks = 0; ks < KS; ++ks) {
            int byte = ((col * C + ks * 32 + lk8) * 2) ^ ((col & 7) << 4);
            bfrag[n][ks] = *reinterpret_cast<const half8*>((const char*)w2img + byte);
        }
    }

    constexpr int TPE = 256 / ET;   // threads per edge; 32 features per thread
    const int e_loc = threadIdx.x / TPE;
    const int part  = threadIdx.x % TPE;
    const int k0 = part * 32;
    const int e = blockIdx.x * ET + e_loc;
    const bool valid = (e < E);
    const int dn = valid ? csr_dst[e] : 0;
    const int sn = valid ? csr_src[e] : 0;
    if (part == 0) dstid[e_loc] = valid ? dn : -1;

    const h2 zz = {(_Float16)0.f, (_Float16)0.f};
    const u16* Ur = U + (size_t)dn * C + k0;
    const u16* Vr = V + (size_t)sn * C + k0;
    #pragma unroll
    for (int j = 0; j < 4; ++j) {
        uint4 uu = {0, 0, 0, 0}, vv = {0, 0, 0, 0};
        if (valid) {
            uu = *reinterpret_cast<const uint4*>(Ur + j * 8);
            vv = *reinterpret_cast<const uint4*>(Vr + j * 8);
        }
        h2 o[4];
        const h2* ua = reinterpret_cast<const h2*>(&uu);
        const h2* va = reinterpret_cast<const h2*>(&vv);
        #pragma unroll
        for (int q = 0; q < 4; ++q)
            o[q] = __builtin_elementwise_max(ua[q] + va[q], zz);
        int byte = ((e_loc * C + k0 + j * 8) * 2) ^ ((e_loc & 7) << 4);
        *reinterpret_cast<uint4*>((char*)at + byte) = *reinterpret_cast<const uint4*>(o);
    }
    __syncthreads();

    f32x4 acc[MPW][NPW] = {};

    #pragma unroll
    for (int ks = 0; ks < KS; ++ks) {
        half8 afrag[MPW];
        #pragma unroll
        for (int m = 0; m < MPW; ++m) {
            int row = (wm * MPW + m) * 16 + lrow;
            int byte = ((row * C + ks * 32 + lk8) * 2) ^ ((row & 7) << 4);
            afrag[m] = *reinterpret_cast<const half8*>((const char*)at + byte);
        }
        #pragma unroll
        for (int m = 0; m < MPW; ++m)
            #pragma unroll
            for (int n = 0; n < NPW; ++n)
                acc[m][n] = __builtin_amdgcn_mfma_f32_16x16x32_f16(
                    afrag[m], bfrag[n][ks], acc[m][n], 0, 0, 0);
    }
    __syncthreads();

    #pragma unroll
    for (int m = 0; m < MPW; ++m) {
        #pragma unroll
        for (int n = 0; n < NPW; ++n) {
            int col = (wn * NPW + n) * 16 + lrow;
            float bb = b2[col];
            #pragma unroll
            for (int j = 0; j < 4; ++j) {
                int row = (wm * MPW + m) * 16 + (lane >> 4) * 4 + j;
                at[row * (C + PAD) + col] = f2h(fmaxf(acc[m][n][j] + bb, 0.f));
            }
        }
    }
    __syncthreads();

    // segmented scan: 256/C groups x C cols; 32 edges per thread
    constexpr int EPS = ET * C / 256;  // == 32
    const int col = threadIdx.x & (C - 1);
    const int e0 = (threadIdx.x / C) * EPS;
    float sum = 0.f;
    int cur = dstid[e0];
    #pragma unroll 4
    for (int ee = e0; ee < e0 + EPS; ++ee) {
        int d = dstid[ee];
        if (d != cur) {
            if (cur >= 0) atomicAdd(&Xout[(size_t)cur * C + col], sum);
            sum = 0.f;
            cur = d;
        }
        sum += h2f(at[ee * (C + PAD) + col]);
    }
    if (cur >= 0) atomicAdd(&Xout[(size_t)cur * C + col], sum);
}

// ---------------------------------------------------------------------------
// Centroid distances via MFMA: dist^2 = |x|^2 - 2 x.c + |c|^2 (fp16 operands)
// ---------------------------------------------------------------------------
__global__ __launch_bounds__(256) void dist_mfma_kernel(
    const float* __restrict__ X, const float* __restrict__ scale,
    const u16* __restrict__ centimg, const float* __restrict__ csq,
    float* __restrict__ dist, int N)
{
    __shared__ u16 ct[112 * 128];
    __shared__ u16 xt[64 * 128];
    __shared__ float xsqp[64][4];
    __shared__ float csqs[112];

    for (int i = threadIdx.x; i < 112 * 128 / 8; i += 256)
        reinterpret_cast<uint4*>(ct)[i] = reinterpret_cast<const uint4*>(centimg)[i];
    if (threadIdx.x < 112) csqs[threadIdx.x] = csq[threadIdx.x];

    const int nl = threadIdx.x >> 2;
    const int part = threadIdx.x & 3;
    const int n = blockIdx.x * 64 + nl;
    const int k0 = part * 32;
    const bool vld = (n < N);
    const float s = vld ? scale[n] : 0.f;

    float ss = 0.f;
    #pragma unroll
    for (int j8 = 0; j8 < 4; ++j8) {
        float4 f0 = {0, 0, 0, 0}, f1 = {0, 0, 0, 0};
        if (vld) {
            f0 = *reinterpret_cast<const float4*>(X + (size_t)n * 128 + k0 + j8 * 8);
            f1 = *reinterpret_cast<const float4*>(X + (size_t)n * 128 + k0 + j8 * 8 + 4);
        }
        float xv[8] = {f0.x * s, f0.y * s, f0.z * s, f0.w * s,
                       f1.x * s, f1.y * s, f1.z * s, f1.w * s};
        u32 o[4];
        #pragma unroll
        for (int q = 0; q < 4; ++q) {
            float lo = h2f(f2h(xv[q * 2]));
            float hi = h2f(f2h(xv[q * 2 + 1]));
            ss += lo * lo + hi * hi;
            o[q] = pack2h(xv[q * 2], xv[q * 2 + 1]);
        }
        int byte = ((nl * 128 + k0 + j8 * 8) * 2) ^ ((nl & 7) << 4);
        *reinterpret_cast<uint4*>((char*)xt + byte) = *reinterpret_cast<uint4*>(o);
    }
    xsqp[nl][part] = ss;
    __syncthreads();

    const int wid = threadIdx.x >> 6;
    const int lane = threadIdx.x & 63;
    const int lrow = lane & 15;
    const int lk8 = (lane >> 4) * 8;

    f32x4 acc[7] = {};
    #pragma unroll
    for (int ks = 0; ks < 4; ++ks) {
        int row = wid * 16 + lrow;
        int byte = ((row * 128 + ks * 32 + lk8) * 2) ^ ((row & 7) << 4);
        half8 afrag = *reinterpret_cast<const half8*>((const char*)xt + byte);
        #pragma unroll
        for (int nn = 0; nn < 7; ++nn) {
            int colr = nn * 16 + lrow;
            int bb = ((colr * 128 + ks * 32 + lk8) * 2) ^ ((colr & 7) << 4);
            half8 bfrag = *reinterpret_cast<const half8*>((const char*)ct + bb);
            acc[nn] = __builtin_amdgcn_mfma_f32_16x16x32_f16(afrag, bfrag, acc[nn], 0, 0, 0);
        }
    }

    float xs[4];
    #pragma unroll
    for (int j = 0; j < 4; ++j) {
        int row = wid * 16 + (lane >> 4) * 4 + j;
        xs[j] = xsqp[row][0] + xsqp[row][1] + xsqp[row][2] + xsqp[row][3];
    }
    #pragma unroll
    for (int nn = 0; nn < 7; ++nn) {
        int colr = nn * 16 + lrow;
        if (colr < NUM_CENTROID) {
            float cq = csqs[colr];
            #pragma unroll
            for (int j = 0; j < 4; ++j) {
                int row = wid * 16 + (lane >> 4) * 4 + j;
                int node = blockIdx.x * 64 + row;
                if (node < N) {
                    float v = xs[j] - 2.f * acc[nn][j] + cq;
                    dist[(size_t)node * NUM_CENTROID + colr] = sqrtf(fmaxf(v, 0.f) + 1e-12f);
                }
            }
        }
    }
}

// ---------------------------------------------------------------------------
// Per-graph pooling + FC
// ---------------------------------------------------------------------------
__global__ __launch_bounds__(128) void pool_fc_kernel(
    const float* __restrict__ dist, const int* __restrict__ gid,
    const float* __restrict__ fc_w, const float* __restrict__ fc_b,
    float* __restrict__ out, int N)
{
    __shared__ float pooled[NUM_CENTROID];
    const int g = blockIdx.x;
    const int t = threadIdx.x;

    int lo = 0, hi = N;
    while (lo < hi) { int mid = (lo + hi) >> 1; if (gid[mid] < g) lo = mid + 1; else hi = mid; }
    const int start = lo;
    hi = N;
    while (lo < hi) { int mid = (lo + hi) >> 1; if (gid[mid] < g + 1) lo = mid + 1; else hi = mid; }
    const int end = lo;

    if (t < NUM_CENTROID) {
        float s = 0.f;
        for (int n = start; n < end; ++n) s += dist[(size_t)n * NUM_CENTROID + t];
        pooled[t] = s / fmaxf((float)(end - start), 1.0f);
    }
    __syncthreads();
    if (t < 2) {
        float o = fc_b[t];
        for (int c = 0; c < NUM_CENTROID; ++c) o += pooled[c] * fc_w[c * 2 + t];
        out[g * 2 + t] = o;
    }
}

// ---------------------------------------------------------------------------
// Host launch
// ---------------------------------------------------------------------------
static const int W1OFF_H[6] = {0, 2048, 4096, 8192, 16384, 32768};
static const int W2OFF_H[6] = {0, 1024, 2048, 6144, 10240, 26624};

extern "C" void kernel_launch(void* const* d_in, const int* in_sizes, int n_in,
                              void* d_out, int out_size, void* d_ws, size_t ws_size,
                              hipStream_t stream) {
    const float* features = (const float*)d_in[0];
    const int*   src      = (const int*)d_in[1];
    const int*   dst      = (const int*)d_in[2];
    const int*   gid      = (const int*)d_in[3];
    const float* gamma    = (const float*)d_in[4];
    const float* beta     = (const float*)d_in[5];
    const float *W1[6], *b1[6], *W2[6], *b2[6];
    for (int i = 0; i < 6; ++i) {
        W1[i] = (const float*)d_in[6 + 4 * i];
        b1[i] = (const float*)d_in[7 + 4 * i];
        W2[i] = (const float*)d_in[8 + 4 * i];
        b2[i] = (const float*)d_in[9 + 4 * i];
    }
    const float* centroids = (const float*)d_in[30];
    const float* fc_w      = (const float*)d_in[31];
    const float* fc_b      = (const float*)d_in[32];

    const int N = N_NODES, E = N_EDGES;

    char* p = (char*)d_ws;
    size_t off = 0;
    auto alloc = [&](size_t bytes) {
        void* r = p + off;
        off += (bytes + 255) & ~(size_t)255;
        return r;
    };

    float* X0bn = (float*)alloc((size_t)N * IN_FEAT * 4);
    char* xz0 = p + off;
    float* XL[6];
    const int LCC[6] = {32, 32, 64, 64, 128, 128};
    for (int i = 0; i < 6; ++i) XL[i] = (float*)alloc((size_t)N * LCC[i] * 4);
    size_t xzbytes = (size_t)((p + off) - xz0);

    u16* Uh = (u16*)alloc((size_t)N * 128 * 2);
    u16* Vh = (u16*)alloc((size_t)N * 128 * 2);
    float* distb = (float*)Uh;  // overlay: U/V dead once dist runs

    int*   row_off = (int*)alloc((size_t)(N + 1) * 4);
    int*   csr_src = (int*)alloc((size_t)E * 4);
    int*   csr_dst = (int*)alloc((size_t)E * 4);
    float* deg_inv = (float*)alloc((size_t)N * 4);
    u16*   w1img   = (u16*)alloc((size_t)W1TOT * 2);
    u16*   w2img   = (u16*)alloc((size_t)W2TOT * 2);
    u16*   centimg = (u16*)alloc((size_t)CTOT * 2);
    float* csq     = (float*)alloc(112 * 4);

    char*  zero0   = (char*)(p + off);
    int*   counts  = (int*)alloc((size_t)N * 4);
    int*   cursor  = (int*)alloc((size_t)N * 4);
    float* bnacc   = (float*)alloc(64);
    size_t zbytes  = (size_t)((char*)(p + off) - zero0);

    (void)hipMemsetAsync(xz0, 0, xzbytes, stream);
    (void)hipMemsetAsync(zero0, 0, zbytes, stream);

    setup1_kernel<<<BN_BLKS + 1875, 256, 0, stream>>>(features, bnacc, dst, counts);
    scan_kernel<<<1, 1024, 0, stream>>>(counts, row_off, deg_inv, N);

    Setup2Args sa;
    sa.dst = dst; sa.src = src; sa.row_off = row_off; sa.cursor = cursor;
    sa.csr_src = csr_src; sa.csr_dst = csr_dst;
    sa.f = features; sa.acc = bnacc; sa.gamma = gamma; sa.beta = beta; sa.X0 = X0bn;
    for (int i = 0; i < 6; ++i) { sa.w1[i] = W1[i]; sa.w2[i] = W2[i]; }
    sa.cent = centroids; sa.w1img = w1img; sa.w2img = w2img;
    sa.centimg = centimg; sa.csq = csq;
    const int S2B = CSR_BLKS + BNN_BLKS + (PREP_TOT + 255) / 256;
    setup2_kernel<<<S2B, 256, 0, stream>>>(sa);

    const int NB = (N + 31) / 32;

    node_mfma_kernel<5, 32, 32><<<NB, 256, 0, stream>>>(
        X0bn, (const float*)nullptr, w1img + W1OFF_H[0], b1[0], Uh, Vh, N);
    edge_agg_kernel<32, 256><<<(E + 255) / 256, 256, 0, stream>>>(
        Uh, Vh, csr_src, csr_dst, w2img + W2OFF_H[0], b2[0], XL[0], E);

    node_mfma_kernel<32, 32, 32><<<NB, 256, 0, stream>>>(
        XL[0], deg_inv, w1img + W1OFF_H[1], b1[1], Uh, Vh, N);
    edge_agg_kernel<32, 256><<<(E + 255) / 256, 256, 0, stream>>>(
        Uh, Vh, csr_src, csr_dst, w2img + W2OFF_H[1], b2[1], XL[1], E);

    node_mfma_kernel<32, 32, 64><<<NB, 256, 0, stream>>>(
        XL[1], deg_inv, w1img + W1OFF_H[2], b1[2], Uh, Vh, N);
    edge_agg_kernel<64, 128><<<(E + 127) / 128, 256, 0, stream>>>(
        Uh, Vh, csr_src, csr_dst, w2img + W2OFF_H[2], b2[2], XL[2], E);

    node_mfma_kernel<64, 64, 64><<<NB, 256, 0, stream>>>(
        XL[2], deg_inv, w1img + W1OFF_H[3], b1[3], Uh, Vh, N);
    edge_agg_kernel<64, 128><<<(E + 127) / 128, 256, 0, stream>>>(
        Uh, Vh, csr_src, csr_dst, w2img + W2OFF_H[3], b2[3], XL[3], E);

    node_mfma_kernel<64, 64, 128><<<NB, 256, 0, stream>>>(
        XL[3], deg_inv, w1img + W1OFF_H[4], b1[4], Uh, Vh, N);
    edge_agg_kernel<128, 64><<<(E + 63) / 64, 256, 0, stream>>>(
        Uh, Vh, csr_src, csr_dst, w2img + W2OFF_H[4], b2[4], XL[4], E);

    node_mfma_kernel<128, 128, 128><<<NB, 256, 0, stream>>>(
        XL[4], deg_inv, w1img + W1OFF_H[5], b1[5], Uh, Vh, N);
    edge_agg_kernel<128, 64><<<(E + 63) / 64, 256, 0, stream>>>(
        Uh, Vh, csr_src, csr_dst, w2img + W2OFF_H[5], b2[5], XL[5], E);

    dist_mfma_kernel<<<(N + 63) / 64, 256, 0, stream>>>(XL[5], deg_inv, centimg, csq, distb, N);
    pool_fc_kernel<<<N_GRAPHS, 128, 0, stream>>>(distb, gid, fc_w, fc_b, (float*)d_out, N);
}